// Round 1
// baseline (1773.441 us; speedup 1.0000x reference)
//
#include <hip/hip_runtime.h>
#include <math.h>

#define BB 4
#define SS 2048
#define DD 1024
#define HHD 16      // heads
#define HD 64       // head dim
#define DH 512      // indexer hidden
#define KSEL 614    // top-k count
#define KPAD 640    // padded to multiple of 64
#define MTOT (BB*SS)

// ---------------- fp32 tiled GEMM: C[M,N] = A[M,K] @ B[N,K]^T + bias (opt ReLU)
#define BM 128
#define BN 128
#define BK 16

template<bool RELU>
__global__ __launch_bounds__(256)
void gemm_nt(const float* __restrict__ A, const float* __restrict__ Bw,
             const float* __restrict__ bias, float* __restrict__ C,
             int M, int N, int K)
{
    __shared__ float As[BK][BM];
    __shared__ float Bs[BK][BN];
    const int t = threadIdx.x;
    const int row0 = blockIdx.y * BM;
    const int col0 = blockIdx.x * BN;
    const int tx = t & 15, ty = t >> 4;
    const int lr = t >> 2;   // 0..63
    const int lc4 = t & 3;   // 0..3

    float acc[8][8];
    #pragma unroll
    for (int i = 0; i < 8; ++i)
        #pragma unroll
        for (int j = 0; j < 8; ++j) acc[i][j] = 0.f;

    for (int k0 = 0; k0 < K; k0 += BK) {
        #pragma unroll
        for (int e = 0; e < 2; ++e) {
            const int r = lr + e * 64;
            float4 av = *reinterpret_cast<const float4*>(&A[(size_t)(row0 + r) * K + k0 + lc4 * 4]);
            As[lc4*4+0][r] = av.x; As[lc4*4+1][r] = av.y;
            As[lc4*4+2][r] = av.z; As[lc4*4+3][r] = av.w;
            float4 bv = *reinterpret_cast<const float4*>(&Bw[(size_t)(col0 + r) * K + k0 + lc4 * 4]);
            Bs[lc4*4+0][r] = bv.x; Bs[lc4*4+1][r] = bv.y;
            Bs[lc4*4+2][r] = bv.z; Bs[lc4*4+3][r] = bv.w;
        }
        __syncthreads();
        #pragma unroll
        for (int kk = 0; kk < BK; ++kk) {
            float af[8], bf[8];
            *reinterpret_cast<float4*>(&af[0]) = *reinterpret_cast<const float4*>(&As[kk][ty*8]);
            *reinterpret_cast<float4*>(&af[4]) = *reinterpret_cast<const float4*>(&As[kk][ty*8+4]);
            *reinterpret_cast<float4*>(&bf[0]) = *reinterpret_cast<const float4*>(&Bs[kk][tx*8]);
            *reinterpret_cast<float4*>(&bf[4]) = *reinterpret_cast<const float4*>(&Bs[kk][tx*8+4]);
            #pragma unroll
            for (int i = 0; i < 8; ++i)
                #pragma unroll
                for (int j = 0; j < 8; ++j)
                    acc[i][j] = fmaf(af[i], bf[j], acc[i][j]);
        }
        __syncthreads();
    }
    #pragma unroll
    for (int i = 0; i < 8; ++i) {
        const int row = row0 + ty*8 + i;
        float out[8];
        #pragma unroll
        for (int j = 0; j < 8; ++j) {
            float v = acc[i][j] + bias[col0 + tx*8 + j];
            if (RELU) v = fmaxf(v, 0.f);
            out[j] = v;
        }
        *reinterpret_cast<float4*>(&C[(size_t)row * N + col0 + tx*8])     = *reinterpret_cast<float4*>(&out[0]);
        *reinterpret_cast<float4*>(&C[(size_t)row * N + col0 + tx*8 + 4]) = *reinterpret_cast<float4*>(&out[4]);
    }
}

// ---------------- importance: imp[row] = h[row,:] . wi2 + bi2   (h is [MTOT, DH])
__global__ __launch_bounds__(256)
void importance_kernel(const float* __restrict__ h, const float* __restrict__ wi2,
                       const float* __restrict__ bi2, float* __restrict__ imp)
{
    const int wid = threadIdx.x >> 6, lane = threadIdx.x & 63;
    const int row = blockIdx.x * 4 + wid;
    const float* hr = h + (size_t)row * DH;
    float s = 0.f;
    #pragma unroll
    for (int i = 0; i < DH/64; ++i)
        s = fmaf(hr[lane + i*64], wi2[lane + i*64], s);
    #pragma unroll
    for (int off = 32; off; off >>= 1) s += __shfl_down(s, off);
    if (lane == 0) imp[row] = s + bi2[0];
}

// ---------------- top-k: exact lax.top_k tie-break (value desc, index asc)
__global__ __launch_bounds__(256)
void rank_kernel(const float* __restrict__ imp, int* __restrict__ flags)
{
    const int b = blockIdx.y;
    const int i = blockIdx.x * 256 + threadIdx.x;  // grid.x = SS/256
    const float* bimp = imp + b * SS;
    const float v = bimp[i];
    int rank = 0;
    for (int j = 0; j < SS; ++j) {
        const float u = bimp[j];
        rank += (u > v) || ((u == v) && (j < i));
    }
    flags[b * SS + i] = (rank < KSEL) ? 1 : 0;
}

__global__ __launch_bounds__(256)
void compact_kernel(const int* __restrict__ flags, int* __restrict__ idxg)
{
    __shared__ int sscan[SS];
    __shared__ int sidx[KSEL];
    const int b = blockIdx.x, t = threadIdx.x;
    for (int i = t; i < SS; i += 256) sscan[i] = flags[b * SS + i];
    __syncthreads();
    for (int off = 1; off < SS; off <<= 1) {
        int vals[SS/256];
        #pragma unroll
        for (int c = 0; c < SS/256; ++c) {
            const int i = t + c * 256;
            int v = sscan[i];
            if (i >= off) v += sscan[i - off];
            vals[c] = v;
        }
        __syncthreads();
        #pragma unroll
        for (int c = 0; c < SS/256; ++c) sscan[t + c * 256] = vals[c];
        __syncthreads();
    }
    for (int i = t; i < SS; i += 256) {
        const int f = flags[b * SS + i];
        if (f) sidx[sscan[i] - 1] = i;   // exclusive pos = inclusive - 1
    }
    __syncthreads();
    for (int p = t; p < KPAD; p += 256)
        idxg[b * KPAD + p] = sidx[min(p, KSEL - 1)];
}

// ---------------- sparse flash attention over gathered keys
#define QT 32
#define KT 64

__global__ __launch_bounds__(256)
void attn_kernel(const float* __restrict__ Qb, const float* __restrict__ Kb,
                 const float* __restrict__ Vb, const int* __restrict__ idxg,
                 float* __restrict__ Ob)
{
    __shared__ float Ks[KT][68];   // stride 68: 16B-aligned rows, bank-spread
    __shared__ float Vs[KT][68];
    __shared__ float Ps[QT][65];

    const int t = threadIdx.x;
    const int qt = blockIdx.x, hh = blockIdx.y, b = blockIdx.z;
    const int q0 = qt * QT;
    const int tq = t >> 3;   // 0..31  (q row in tile)
    const int tk = t & 7;    // 0..7

    // Q row into registers (8 threads per q share the row; L2 broadcasts)
    float qreg[HD];
    {
        const float* qrow = Qb + ((size_t)(b * SS + q0 + tq)) * DD + hh * HD;
        #pragma unroll
        for (int d4 = 0; d4 < HD/4; ++d4)
            *reinterpret_cast<float4*>(&qreg[d4*4]) = *reinterpret_cast<const float4*>(&qrow[d4*4]);
    }

    float acc[8];
    #pragma unroll
    for (int i = 0; i < 8; ++i) acc[i] = 0.f;
    float mrun = -INFINITY, lrun = 0.f;

    const int* bidx = idxg + b * KPAD;

    for (int c = 0; c < KPAD/KT; ++c) {
        // gather-stage K/V chunk: 64 rows x 64 floats each
        #pragma unroll
        for (int e = 0; e < 4; ++e) {
            const int ei = t + e * 256;
            const int r = ei >> 4, c4 = ei & 15;
            const int krow = bidx[c * KT + r];
            const size_t base = ((size_t)(b * SS + krow)) * DD + hh * HD + c4 * 4;
            *reinterpret_cast<float4*>(&Ks[r][c4*4]) = *reinterpret_cast<const float4*>(&Kb[base]);
            *reinterpret_cast<float4*>(&Vs[r][c4*4]) = *reinterpret_cast<const float4*>(&Vb[base]);
        }
        __syncthreads();

        // scores: this thread owns keys j = jj*8 + tk (bank-disjoint rows)
        float sc[8];
        #pragma unroll
        for (int jj = 0; jj < 8; ++jj) sc[jj] = 0.f;
        #pragma unroll
        for (int d4 = 0; d4 < HD/4; ++d4) {
            #pragma unroll
            for (int jj = 0; jj < 8; ++jj) {
                float4 kf = *reinterpret_cast<const float4*>(&Ks[jj*8 + tk][d4*4]);
                sc[jj] = fmaf(qreg[d4*4+0], kf.x, sc[jj]);
                sc[jj] = fmaf(qreg[d4*4+1], kf.y, sc[jj]);
                sc[jj] = fmaf(qreg[d4*4+2], kf.z, sc[jj]);
                sc[jj] = fmaf(qreg[d4*4+3], kf.w, sc[jj]);
            }
        }
        float cmax = -INFINITY;
        #pragma unroll
        for (int jj = 0; jj < 8; ++jj) {
            const int kpos = c * KT + jj*8 + tk;
            sc[jj] = (kpos < KSEL) ? sc[jj] * 0.125f : -INFINITY;
            cmax = fmaxf(cmax, sc[jj]);
        }
        #pragma unroll
        for (int off = 1; off < 8; off <<= 1) cmax = fmaxf(cmax, __shfl_xor(cmax, off));
        const float newm = fmaxf(mrun, cmax);
        const float scale = expf(mrun - newm);   // first chunk: exp(-inf)=0
        float p[8];
        float csum = 0.f;
        #pragma unroll
        for (int jj = 0; jj < 8; ++jj) { p[jj] = expf(sc[jj] - newm); csum += p[jj]; }
        #pragma unroll
        for (int off = 1; off < 8; off <<= 1) csum += __shfl_xor(csum, off);
        lrun = lrun * scale + csum;
        mrun = newm;
        #pragma unroll
        for (int i = 0; i < 8; ++i) acc[i] *= scale;
        #pragma unroll
        for (int jj = 0; jj < 8; ++jj) Ps[tq][jj*8 + tk] = p[jj];
        __syncthreads();

        // PV: acc[d] += sum_kk P[tq][kk] * V[kk][tk*8 + d]
        #pragma unroll 8
        for (int kk = 0; kk < KT; ++kk) {
            const float pv = Ps[tq][kk];
            float4 va = *reinterpret_cast<const float4*>(&Vs[kk][tk*8]);
            float4 vb = *reinterpret_cast<const float4*>(&Vs[kk][tk*8+4]);
            acc[0] = fmaf(pv, va.x, acc[0]);
            acc[1] = fmaf(pv, va.y, acc[1]);
            acc[2] = fmaf(pv, va.z, acc[2]);
            acc[3] = fmaf(pv, va.w, acc[3]);
            acc[4] = fmaf(pv, vb.x, acc[4]);
            acc[5] = fmaf(pv, vb.y, acc[5]);
            acc[6] = fmaf(pv, vb.z, acc[6]);
            acc[7] = fmaf(pv, vb.w, acc[7]);
        }
        __syncthreads();
    }

    const float inv = 1.f / lrun;
    float o[8];
    #pragma unroll
    for (int i = 0; i < 8; ++i) o[i] = acc[i] * inv;
    float* orow = Ob + ((size_t)(b * SS + q0 + tq)) * DD + hh * HD + tk * 8;
    *reinterpret_cast<float4*>(&orow[0]) = *reinterpret_cast<float4*>(&o[0]);
    *reinterpret_cast<float4*>(&orow[4]) = *reinterpret_cast<float4*>(&o[4]);
}

extern "C" void kernel_launch(void* const* d_in, const int* in_sizes, int n_in,
                              void* d_out, int out_size, void* d_ws, size_t ws_size,
                              hipStream_t stream)
{
    const float* x   = (const float*)d_in[0];
    const float* wq  = (const float*)d_in[1];
    const float* bq  = (const float*)d_in[2];
    const float* wk  = (const float*)d_in[3];
    const float* bk  = (const float*)d_in[4];
    const float* wv  = (const float*)d_in[5];
    const float* bv  = (const float*)d_in[6];
    const float* wo  = (const float*)d_in[7];
    const float* bo  = (const float*)d_in[8];
    const float* wi1 = (const float*)d_in[9];
    const float* bi1 = (const float*)d_in[10];
    const float* wi2 = (const float*)d_in[11];
    const float* bi2 = (const float*)d_in[12];
    float* out = (float*)d_out;

    const size_t NM = (size_t)MTOT * DD;   // 8M floats
    float* Qw = (float*)d_ws;
    float* Kw = Qw + NM;
    float* Vw = Kw + NM;
    float* SC = Vw + NM;        // 8M floats scratch: h (first 4M), then attn-out (all 8M)
    float* Hw = SC;             // h is dead before attention runs
    float* AO = SC;
    float* imp = SC + NM;
    int* flags = (int*)(imp + MTOT);
    int* idxg  = flags + MTOT;

    // 1. indexer h = relu(x @ wi1^T + bi1)
    gemm_nt<true><<<dim3(DH/BN, MTOT/BM), 256, 0, stream>>>(x, wi1, bi1, Hw, MTOT, DH, DD);
    // 2. importance = h @ wi2^T + bi2
    importance_kernel<<<MTOT/4, 256, 0, stream>>>(Hw, wi2, bi2, imp);
    // 3. top-k flags + compaction
    rank_kernel<<<dim3(SS/256, BB), 256, 0, stream>>>(imp, flags);
    compact_kernel<<<BB, 256, 0, stream>>>(flags, idxg);
    // 4. Q/K/V projections
    gemm_nt<false><<<dim3(DD/BN, MTOT/BM), 256, 0, stream>>>(x, wq, bq, Qw, MTOT, DD, DD);
    gemm_nt<false><<<dim3(DD/BN, MTOT/BM), 256, 0, stream>>>(x, wk, bk, Kw, MTOT, DD, DD);
    gemm_nt<false><<<dim3(DD/BN, MTOT/BM), 256, 0, stream>>>(x, wv, bv, Vw, MTOT, DD, DD);
    // 5. sparse flash attention (h region now dead; AO overwrites it)
    attn_kernel<<<dim3(SS/QT, HHD, BB), 256, 0, stream>>>(Qw, Kw, Vw, idxg, AO);
    // 6. output projection
    gemm_nt<false><<<dim3(DD/BN, MTOT/BM), 256, 0, stream>>>(AO, wo, bo, out, MTOT, DD, DD);
}

// Round 2
// 1134.008 us; speedup vs baseline: 1.5639x; 1.5639x over previous
//
#include <hip/hip_runtime.h>
#include <math.h>

#define BB 4
#define SS 2048
#define DD 1024
#define HHD 16      // heads
#define HD 64       // head dim
#define DH 512      // indexer hidden
#define KSEL 614    // top-k count
#define KPAD 640    // padded to multiple of 64
#define MTOT (BB*SS)
#define QKVS 3072   // fused QKV row stride

typedef __attribute__((ext_vector_type(8))) short bf16x8;
typedef __attribute__((ext_vector_type(4))) float f32x4;

#define LDS_CAST(p) ((__attribute__((address_space(3))) void*)(p))
#define GLB_CAST(p) ((const __attribute__((address_space(1))) void*)(p))

// ---------------- fp32 tiled GEMM (indexer only): C[M,N] = A[M,K] @ B[N,K]^T + bias, ReLU
#define BM 128
#define BN 128
#define BK 16

template<bool RELU>
__global__ __launch_bounds__(256)
void gemm_nt(const float* __restrict__ A, const float* __restrict__ Bw,
             const float* __restrict__ bias, float* __restrict__ C,
             int M, int N, int K)
{
    __shared__ float As[BK][BM];
    __shared__ float Bs[BK][BN];
    const int t = threadIdx.x;
    const int row0 = blockIdx.y * BM;
    const int col0 = blockIdx.x * BN;
    const int tx = t & 15, ty = t >> 4;
    const int lr = t >> 2;   // 0..63
    const int lc4 = t & 3;   // 0..3

    float acc[8][8];
    #pragma unroll
    for (int i = 0; i < 8; ++i)
        #pragma unroll
        for (int j = 0; j < 8; ++j) acc[i][j] = 0.f;

    for (int k0 = 0; k0 < K; k0 += BK) {
        #pragma unroll
        for (int e = 0; e < 2; ++e) {
            const int r = lr + e * 64;
            float4 av = *reinterpret_cast<const float4*>(&A[(size_t)(row0 + r) * K + k0 + lc4 * 4]);
            As[lc4*4+0][r] = av.x; As[lc4*4+1][r] = av.y;
            As[lc4*4+2][r] = av.z; As[lc4*4+3][r] = av.w;
            float4 bv = *reinterpret_cast<const float4*>(&Bw[(size_t)(col0 + r) * K + k0 + lc4 * 4]);
            Bs[lc4*4+0][r] = bv.x; Bs[lc4*4+1][r] = bv.y;
            Bs[lc4*4+2][r] = bv.z; Bs[lc4*4+3][r] = bv.w;
        }
        __syncthreads();
        #pragma unroll
        for (int kk = 0; kk < BK; ++kk) {
            float af[8], bf[8];
            *reinterpret_cast<float4*>(&af[0]) = *reinterpret_cast<const float4*>(&As[kk][ty*8]);
            *reinterpret_cast<float4*>(&af[4]) = *reinterpret_cast<const float4*>(&As[kk][ty*8+4]);
            *reinterpret_cast<float4*>(&bf[0]) = *reinterpret_cast<const float4*>(&Bs[kk][tx*8]);
            *reinterpret_cast<float4*>(&bf[4]) = *reinterpret_cast<const float4*>(&Bs[kk][tx*8+4]);
            #pragma unroll
            for (int i = 0; i < 8; ++i)
                #pragma unroll
                for (int j = 0; j < 8; ++j)
                    acc[i][j] = fmaf(af[i], bf[j], acc[i][j]);
        }
        __syncthreads();
    }
    #pragma unroll
    for (int i = 0; i < 8; ++i) {
        const int row = row0 + ty*8 + i;
        float out[8];
        #pragma unroll
        for (int j = 0; j < 8; ++j) {
            float v = acc[i][j] + bias[col0 + tx*8 + j];
            if (RELU) v = fmaxf(v, 0.f);
            out[j] = v;
        }
        *reinterpret_cast<float4*>(&C[(size_t)row * N + col0 + tx*8])     = *reinterpret_cast<float4*>(&out[0]);
        *reinterpret_cast<float4*>(&C[(size_t)row * N + col0 + tx*8 + 4]) = *reinterpret_cast<float4*>(&out[4]);
    }
}

// ---------------- fp32 -> bf16 hi/lo split (RNE both)
__device__ inline void split1(float v, short& h, short& l)
{
    unsigned u = __builtin_bit_cast(unsigned, v);
    unsigned hr = (u + 0x7FFFu + ((u >> 16) & 1u)) >> 16;
    h = (short)hr;
    float hf = __builtin_bit_cast(float, hr << 16);
    float res = v - hf;
    unsigned u2 = __builtin_bit_cast(unsigned, res);
    unsigned lr = (u2 + 0x7FFFu + ((u2 >> 16) & 1u)) >> 16;
    l = (short)lr;
}

__global__ __launch_bounds__(256)
void split_convert(const float* __restrict__ in, short* __restrict__ hi,
                   short* __restrict__ lo, int n4)
{
    const int i = blockIdx.x * 256 + threadIdx.x;
    if (i >= n4) return;
    float4 v = reinterpret_cast<const float4*>(in)[i];
    short4 h, l;
    split1(v.x, h.x, l.x);
    split1(v.y, h.y, l.y);
    split1(v.z, h.z, l.z);
    split1(v.w, h.w, l.w);
    reinterpret_cast<short4*>(hi)[i] = h;
    reinterpret_cast<short4*>(lo)[i] = l;
}

__global__ __launch_bounds__(256)
void concat_bias(const float* __restrict__ a, const float* __restrict__ b,
                 const float* __restrict__ c, float* __restrict__ o)
{
    const int i = blockIdx.x * 256 + threadIdx.x;   // 3072
    o[i] = (i < 1024) ? a[i] : ((i < 2048) ? b[i - 1024] : c[i - 2048]);
}

// ---------------- split-bf16 MFMA GEMM: C[M,N] = (Ahi+Alo)[M,K] @ (Bhi+Blo)[N,K]^T + bias
// 128x128 tile, BK=32, 4 waves (2x2 of 64x64), 3 MFMA per fragment pair (drop lo*lo).
__global__ __launch_bounds__(256)
void gemm_split(const short* __restrict__ Ahi, const short* __restrict__ Alo,
                const short* __restrict__ Bhi, const short* __restrict__ Blo,
                const float* __restrict__ bias, float* __restrict__ C,
                int M, int N, int K)
{
    __shared__ short sAh[128*32];
    __shared__ short sAl[128*32];
    __shared__ short sBh[128*32];
    __shared__ short sBl[128*32];

    const int t = threadIdx.x;
    const int lane = t & 63, wid = t >> 6;
    const int wm = wid >> 1, wn = wid & 1;
    const int row0 = blockIdx.y * 128, col0 = blockIdx.x * 128;
    const int g = lane >> 4, r = lane & 15;
    const int sw = g ^ ((lane >> 2) & 3);    // swizzled slot for frag reads (involution)
    const int srow = lane >> 2;              // staging: row within 16-row chunk
    const int sslot = lane & 3;              // staging: 16B slot within 64B row

    f32x4 acc[4][4];
    #pragma unroll
    for (int mt = 0; mt < 4; ++mt)
        #pragma unroll
        for (int nt = 0; nt < 4; ++nt) acc[mt][nt] = (f32x4){0.f, 0.f, 0.f, 0.f};

    for (int k0 = 0; k0 < K; k0 += 32) {
        #pragma unroll
        for (int i = 0; i < 2; ++i) {
            const int rl = wid * 32 + i * 16 + srow;               // row_local 0..127
            const int scol = k0 + ((sslot ^ ((rl >> 2) & 3)) << 3); // pre-swizzled global col
            const size_t ga = (size_t)(row0 + rl) * K + scol;
            const size_t gb = (size_t)(col0 + rl) * K + scol;
            const int ldso = (wid * 32 + i * 16) * 32;             // uniform LDS elem offset
            __builtin_amdgcn_global_load_lds(GLB_CAST(Ahi + ga), LDS_CAST(sAh + ldso), 16, 0, 0);
            __builtin_amdgcn_global_load_lds(GLB_CAST(Alo + ga), LDS_CAST(sAl + ldso), 16, 0, 0);
            __builtin_amdgcn_global_load_lds(GLB_CAST(Bhi + gb), LDS_CAST(sBh + ldso), 16, 0, 0);
            __builtin_amdgcn_global_load_lds(GLB_CAST(Blo + gb), LDS_CAST(sBl + ldso), 16, 0, 0);
        }
        __syncthreads();

        bf16x8 ah[4], al[4], bh[4], bl[4];
        #pragma unroll
        for (int mt = 0; mt < 4; ++mt) {
            const int row = wm * 64 + mt * 16 + r;
            ah[mt] = *reinterpret_cast<const bf16x8*>(sAh + row * 32 + sw * 8);
            al[mt] = *reinterpret_cast<const bf16x8*>(sAl + row * 32 + sw * 8);
        }
        #pragma unroll
        for (int nt = 0; nt < 4; ++nt) {
            const int row = wn * 64 + nt * 16 + r;
            bh[nt] = *reinterpret_cast<const bf16x8*>(sBh + row * 32 + sw * 8);
            bl[nt] = *reinterpret_cast<const bf16x8*>(sBl + row * 32 + sw * 8);
        }
        #pragma unroll
        for (int mt = 0; mt < 4; ++mt)
            #pragma unroll
            for (int nt = 0; nt < 4; ++nt) {
                acc[mt][nt] = __builtin_amdgcn_mfma_f32_16x16x32_bf16(ah[mt], bh[nt], acc[mt][nt], 0, 0, 0);
                acc[mt][nt] = __builtin_amdgcn_mfma_f32_16x16x32_bf16(ah[mt], bl[nt], acc[mt][nt], 0, 0, 0);
                acc[mt][nt] = __builtin_amdgcn_mfma_f32_16x16x32_bf16(al[mt], bh[nt], acc[mt][nt], 0, 0, 0);
            }
        __syncthreads();
    }

    #pragma unroll
    for (int nt = 0; nt < 4; ++nt) {
        const int col = col0 + wn * 64 + nt * 16 + r;
        const float bv = bias[col];
        #pragma unroll
        for (int mt = 0; mt < 4; ++mt) {
            #pragma unroll
            for (int e = 0; e < 4; ++e) {
                const int row = row0 + wm * 64 + mt * 16 + 4 * g + e;
                C[(size_t)row * N + col] = acc[mt][nt][e] + bv;
            }
        }
    }
}

// ---------------- importance: imp[row] = h[row,:] . wi2 + bi2
__global__ __launch_bounds__(256)
void importance_kernel(const float* __restrict__ h, const float* __restrict__ wi2,
                       const float* __restrict__ bi2, float* __restrict__ imp)
{
    const int wid = threadIdx.x >> 6, lane = threadIdx.x & 63;
    const int row = blockIdx.x * 4 + wid;
    const float* hr = h + (size_t)row * DH;
    float s = 0.f;
    #pragma unroll
    for (int i = 0; i < DH/64; ++i)
        s = fmaf(hr[lane + i*64], wi2[lane + i*64], s);
    #pragma unroll
    for (int off = 32; off; off >>= 1) s += __shfl_down(s, off);
    if (lane == 0) imp[row] = s + bi2[0];
}

// ---------------- top-k: exact lax.top_k tie-break (value desc, index asc)
__global__ __launch_bounds__(256)
void rank_kernel(const float* __restrict__ imp, int* __restrict__ flags)
{
    const int b = blockIdx.y;
    const int i = blockIdx.x * 256 + threadIdx.x;
    const float* bimp = imp + b * SS;
    const float v = bimp[i];
    int rank = 0;
    for (int j = 0; j < SS; ++j) {
        const float u = bimp[j];
        rank += (u > v) || ((u == v) && (j < i));
    }
    flags[b * SS + i] = (rank < KSEL) ? 1 : 0;
}

__global__ __launch_bounds__(256)
void compact_kernel(const int* __restrict__ flags, int* __restrict__ idxg)
{
    __shared__ int sscan[SS];
    __shared__ int sidx[KSEL];
    const int b = blockIdx.x, t = threadIdx.x;
    for (int i = t; i < SS; i += 256) sscan[i] = flags[b * SS + i];
    __syncthreads();
    for (int off = 1; off < SS; off <<= 1) {
        int vals[SS/256];
        #pragma unroll
        for (int c = 0; c < SS/256; ++c) {
            const int i = t + c * 256;
            int v = sscan[i];
            if (i >= off) v += sscan[i - off];
            vals[c] = v;
        }
        __syncthreads();
        #pragma unroll
        for (int c = 0; c < SS/256; ++c) sscan[t + c * 256] = vals[c];
        __syncthreads();
    }
    for (int i = t; i < SS; i += 256) {
        const int f = flags[b * SS + i];
        if (f) sidx[sscan[i] - 1] = i;
    }
    __syncthreads();
    for (int p = t; p < KPAD; p += 256)
        idxg[b * KPAD + p] = sidx[min(p, KSEL - 1)];
}

// ---------------- sparse flash attention over gathered keys (reads fused QKV, stride 3072)
#define QT 32
#define KT 64

__global__ __launch_bounds__(256)
void attn_kernel(const float* __restrict__ QKV, const int* __restrict__ idxg,
                 float* __restrict__ Ob)
{
    __shared__ float Ks[KT][68];
    __shared__ float Vs[KT][68];
    __shared__ float Ps[QT][65];

    const int t = threadIdx.x;
    const int qt = blockIdx.x, hh = blockIdx.y, b = blockIdx.z;
    const int q0 = qt * QT;
    const int tq = t >> 3;   // 0..31
    const int tk = t & 7;    // 0..7

    float qreg[HD];
    {
        const float* qrow = QKV + (size_t)(b * SS + q0 + tq) * QKVS + hh * HD;
        #pragma unroll
        for (int d4 = 0; d4 < HD/4; ++d4)
            *reinterpret_cast<float4*>(&qreg[d4*4]) = *reinterpret_cast<const float4*>(&qrow[d4*4]);
    }

    float acc[8];
    #pragma unroll
    for (int i = 0; i < 8; ++i) acc[i] = 0.f;
    float mrun = -INFINITY, lrun = 0.f;

    const int* bidx = idxg + b * KPAD;

    for (int c = 0; c < KPAD/KT; ++c) {
        #pragma unroll
        for (int e = 0; e < 4; ++e) {
            const int ei = t + e * 256;
            const int r = ei >> 4, c4 = ei & 15;
            const int krow = bidx[c * KT + r];
            const size_t base = (size_t)(b * SS + krow) * QKVS + 1024 + hh * HD + c4 * 4;
            *reinterpret_cast<float4*>(&Ks[r][c4*4]) = *reinterpret_cast<const float4*>(&QKV[base]);
            *reinterpret_cast<float4*>(&Vs[r][c4*4]) = *reinterpret_cast<const float4*>(&QKV[base + 1024]);
        }
        __syncthreads();

        float sc[8];
        #pragma unroll
        for (int jj = 0; jj < 8; ++jj) sc[jj] = 0.f;
        #pragma unroll
        for (int d4 = 0; d4 < HD/4; ++d4) {
            #pragma unroll
            for (int jj = 0; jj < 8; ++jj) {
                float4 kf = *reinterpret_cast<const float4*>(&Ks[jj*8 + tk][d4*4]);
                sc[jj] = fmaf(qreg[d4*4+0], kf.x, sc[jj]);
                sc[jj] = fmaf(qreg[d4*4+1], kf.y, sc[jj]);
                sc[jj] = fmaf(qreg[d4*4+2], kf.z, sc[jj]);
                sc[jj] = fmaf(qreg[d4*4+3], kf.w, sc[jj]);
            }
        }
        float cmax = -INFINITY;
        #pragma unroll
        for (int jj = 0; jj < 8; ++jj) {
            const int kpos = c * KT + jj*8 + tk;
            sc[jj] = (kpos < KSEL) ? sc[jj] * 0.125f : -INFINITY;
            cmax = fmaxf(cmax, sc[jj]);
        }
        #pragma unroll
        for (int off = 1; off < 8; off <<= 1) cmax = fmaxf(cmax, __shfl_xor(cmax, off));
        const float newm = fmaxf(mrun, cmax);
        const float scale = expf(mrun - newm);
        float p[8];
        float csum = 0.f;
        #pragma unroll
        for (int jj = 0; jj < 8; ++jj) { p[jj] = expf(sc[jj] - newm); csum += p[jj]; }
        #pragma unroll
        for (int off = 1; off < 8; off <<= 1) csum += __shfl_xor(csum, off);
        lrun = lrun * scale + csum;
        mrun = newm;
        #pragma unroll
        for (int i = 0; i < 8; ++i) acc[i] *= scale;
        #pragma unroll
        for (int jj = 0; jj < 8; ++jj) Ps[tq][jj*8 + tk] = p[jj];
        __syncthreads();

        #pragma unroll 8
        for (int kk = 0; kk < KT; ++kk) {
            const float pv = Ps[tq][kk];
            float4 va = *reinterpret_cast<const float4*>(&Vs[kk][tk*8]);
            float4 vb = *reinterpret_cast<const float4*>(&Vs[kk][tk*8+4]);
            acc[0] = fmaf(pv, va.x, acc[0]);
            acc[1] = fmaf(pv, va.y, acc[1]);
            acc[2] = fmaf(pv, va.z, acc[2]);
            acc[3] = fmaf(pv, va.w, acc[3]);
            acc[4] = fmaf(pv, vb.x, acc[4]);
            acc[5] = fmaf(pv, vb.y, acc[5]);
            acc[6] = fmaf(pv, vb.z, acc[6]);
            acc[7] = fmaf(pv, vb.w, acc[7]);
        }
        __syncthreads();
    }

    const float inv = 1.f / lrun;
    float o[8];
    #pragma unroll
    for (int i = 0; i < 8; ++i) o[i] = acc[i] * inv;
    float* orow = Ob + (size_t)(b * SS + q0 + tq) * DD + hh * HD + tk * 8;
    *reinterpret_cast<float4*>(&orow[0]) = *reinterpret_cast<float4*>(&o[0]);
    *reinterpret_cast<float4*>(&orow[4]) = *reinterpret_cast<float4*>(&o[4]);
}

extern "C" void kernel_launch(void* const* d_in, const int* in_sizes, int n_in,
                              void* d_out, int out_size, void* d_ws, size_t ws_size,
                              hipStream_t stream)
{
    const float* x   = (const float*)d_in[0];
    const float* wq  = (const float*)d_in[1];
    const float* bq  = (const float*)d_in[2];
    const float* wk  = (const float*)d_in[3];
    const float* bk  = (const float*)d_in[4];
    const float* wv  = (const float*)d_in[5];
    const float* bv  = (const float*)d_in[6];
    const float* wo  = (const float*)d_in[7];
    const float* bo  = (const float*)d_in[8];
    const float* wi1 = (const float*)d_in[9];
    const float* bi1 = (const float*)d_in[10];
    const float* wi2 = (const float*)d_in[11];
    const float* bi2 = (const float*)d_in[12];
    float* out = (float*)d_out;

    const size_t MB = 1ull << 20;
    char* W = (char*)d_ws;
    // phase-1 aliases
    short* x_hi  = (short*)(W + 0);          // 16 MB
    short* x_lo  = (short*)(W + 16*MB);      // 16 MB
    float* QKV   = (float*)(W + 32*MB);      // 96 MB (8192 x 3072 f32)
    short* Bq_hi = (short*)(W + 128*MB);     // 6 MB (3072 x 1024 bf16)
    short* Bq_lo = (short*)(W + 134*MB);     // 6 MB
    short* wo_hi = (short*)(W + 140*MB);     // 2 MB
    short* wo_lo = (short*)(W + 142*MB);     // 2 MB
    float* Hw    = (float*)(W + 144*MB);     // 16 MB (8192 x 512 f32)
    float* bqkv  = (float*)(W + 160*MB);     // 12 KB
    float* imp   = (float*)(W + 160*MB + 64*1024);
    int*   flags = (int*)(W + 160*MB + 128*1024);
    int*   idxg  = (int*)(W + 160*MB + 192*1024);
    // phase-2 aliases (after earlier buffers are dead)
    float* AO    = (float*)(W + 0);          // 32 MB, overwrites x_hi/x_lo
    short* AO_hi = (short*)(W + 32*MB);      // 16 MB, overwrites QKV
    short* AO_lo = (short*)(W + 48*MB);      // 16 MB

    const size_t NM = (size_t)MTOT * DD;     // 8M elements

    // 0. splits + fused bias
    split_convert<<<(NM/4 + 255)/256, 256, 0, stream>>>(x, x_hi, x_lo, NM/4);
    split_convert<<<(DD*DD/4 + 255)/256, 256, 0, stream>>>(wq, Bq_hi,             Bq_lo,             DD*DD/4);
    split_convert<<<(DD*DD/4 + 255)/256, 256, 0, stream>>>(wk, Bq_hi + DD*DD,     Bq_lo + DD*DD,     DD*DD/4);
    split_convert<<<(DD*DD/4 + 255)/256, 256, 0, stream>>>(wv, Bq_hi + 2*DD*DD,   Bq_lo + 2*DD*DD,   DD*DD/4);
    split_convert<<<(DD*DD/4 + 255)/256, 256, 0, stream>>>(wo, wo_hi, wo_lo, DD*DD/4);
    concat_bias<<<QKVS/256, 256, 0, stream>>>(bq, bk, bv, bqkv);

    // 1-3. indexer (exact fp32 path for top-k stability)
    gemm_nt<true><<<dim3(DH/BN, MTOT/BM), 256, 0, stream>>>(x, wi1, bi1, Hw, MTOT, DH, DD);
    importance_kernel<<<MTOT/4, 256, 0, stream>>>(Hw, wi2, bi2, imp);
    rank_kernel<<<dim3(SS/256, BB), 256, 0, stream>>>(imp, flags);
    compact_kernel<<<BB, 256, 0, stream>>>(flags, idxg);

    // 4. fused QKV projection (split-bf16 MFMA): [8192,3072] = x @ [Wq;Wk;Wv]^T
    gemm_split<<<dim3(QKVS/128, MTOT/128), 256, 0, stream>>>(
        x_hi, x_lo, Bq_hi, Bq_lo, bqkv, QKV, MTOT, QKVS, DD);

    // 5. sparse flash attention (x_hi/x_lo dead -> AO overwrites them)
    attn_kernel<<<dim3(SS/QT, HHD, BB), 256, 0, stream>>>(QKV, idxg, AO);

    // 6. split AO (QKV dead -> AO_hi/AO_lo overwrite it)
    split_convert<<<(NM/4 + 255)/256, 256, 0, stream>>>(AO, AO_hi, AO_lo, NM/4);

    // 7. output projection (split-bf16 MFMA)
    gemm_split<<<dim3(DD/128, MTOT/128), 256, 0, stream>>>(
        AO_hi, AO_lo, wo_hi, wo_lo, bo, out, MTOT, DD, DD);
}

// Round 3
// 598.781 us; speedup vs baseline: 2.9618x; 1.8939x over previous
//
#include <hip/hip_runtime.h>
#include <math.h>

#define BB 4
#define SS 2048
#define DD 1024
#define HHD 16      // heads
#define HD 64       // head dim
#define DH 512      // indexer hidden
#define KSEL 614    // top-k count
#define KPAD 640    // padded to multiple of 64
#define MTOT (BB*SS)
#define QKVS 3072   // fused QKV row stride
#define NCH (KPAD/64)

typedef __attribute__((ext_vector_type(8))) short bf16x8;
typedef __attribute__((ext_vector_type(4))) float f32x4;

#define LDS_CAST(p) ((__attribute__((address_space(3))) void*)(p))
#define GLB_CAST(p) ((const __attribute__((address_space(1))) void*)(p))

// ---------------- fp32 tiled GEMM (indexer only): C[M,N] = A[M,K] @ B[N,K]^T + bias, ReLU
#define BM 128
#define BN 128
#define BK 16

template<bool RELU>
__global__ __launch_bounds__(256)
void gemm_nt(const float* __restrict__ A, const float* __restrict__ Bw,
             const float* __restrict__ bias, float* __restrict__ C,
             int M, int N, int K)
{
    __shared__ float As[BK][BM];
    __shared__ float Bs[BK][BN];
    const int t = threadIdx.x;
    const int row0 = blockIdx.y * BM;
    const int col0 = blockIdx.x * BN;
    const int tx = t & 15, ty = t >> 4;
    const int lr = t >> 2;
    const int lc4 = t & 3;

    float acc[8][8];
    #pragma unroll
    for (int i = 0; i < 8; ++i)
        #pragma unroll
        for (int j = 0; j < 8; ++j) acc[i][j] = 0.f;

    for (int k0 = 0; k0 < K; k0 += BK) {
        #pragma unroll
        for (int e = 0; e < 2; ++e) {
            const int r = lr + e * 64;
            float4 av = *reinterpret_cast<const float4*>(&A[(size_t)(row0 + r) * K + k0 + lc4 * 4]);
            As[lc4*4+0][r] = av.x; As[lc4*4+1][r] = av.y;
            As[lc4*4+2][r] = av.z; As[lc4*4+3][r] = av.w;
            float4 bv = *reinterpret_cast<const float4*>(&Bw[(size_t)(col0 + r) * K + k0 + lc4 * 4]);
            Bs[lc4*4+0][r] = bv.x; Bs[lc4*4+1][r] = bv.y;
            Bs[lc4*4+2][r] = bv.z; Bs[lc4*4+3][r] = bv.w;
        }
        __syncthreads();
        #pragma unroll
        for (int kk = 0; kk < BK; ++kk) {
            float af[8], bf[8];
            *reinterpret_cast<float4*>(&af[0]) = *reinterpret_cast<const float4*>(&As[kk][ty*8]);
            *reinterpret_cast<float4*>(&af[4]) = *reinterpret_cast<const float4*>(&As[kk][ty*8+4]);
            *reinterpret_cast<float4*>(&bf[0]) = *reinterpret_cast<const float4*>(&Bs[kk][tx*8]);
            *reinterpret_cast<float4*>(&bf[4]) = *reinterpret_cast<const float4*>(&Bs[kk][tx*8+4]);
            #pragma unroll
            for (int i = 0; i < 8; ++i)
                #pragma unroll
                for (int j = 0; j < 8; ++j)
                    acc[i][j] = fmaf(af[i], bf[j], acc[i][j]);
        }
        __syncthreads();
    }
    #pragma unroll
    for (int i = 0; i < 8; ++i) {
        const int row = row0 + ty*8 + i;
        float out[8];
        #pragma unroll
        for (int j = 0; j < 8; ++j) {
            float v = acc[i][j] + bias[col0 + tx*8 + j];
            if (RELU) v = fmaxf(v, 0.f);
            out[j] = v;
        }
        *reinterpret_cast<float4*>(&C[(size_t)row * N + col0 + tx*8])     = *reinterpret_cast<float4*>(&out[0]);
        *reinterpret_cast<float4*>(&C[(size_t)row * N + col0 + tx*8 + 4]) = *reinterpret_cast<float4*>(&out[4]);
    }
}

// ---------------- fp32 -> bf16 helpers (RNE)
__device__ inline short bf16rne(float v)
{
    unsigned u = __builtin_bit_cast(unsigned, v);
    return (short)((u + 0x7FFFu + ((u >> 16) & 1u)) >> 16);
}

__device__ inline void split1(float v, short& h, short& l)
{
    unsigned u = __builtin_bit_cast(unsigned, v);
    unsigned hr = (u + 0x7FFFu + ((u >> 16) & 1u)) >> 16;
    h = (short)hr;
    float hf = __builtin_bit_cast(float, hr << 16);
    float res = v - hf;
    unsigned u2 = __builtin_bit_cast(unsigned, res);
    unsigned lr = (u2 + 0x7FFFu + ((u2 >> 16) & 1u)) >> 16;
    l = (short)lr;
}

__device__ inline bf16x8 pack8(float4 a, float4 b)
{
    bf16x8 o;
    o[0]=bf16rne(a.x); o[1]=bf16rne(a.y); o[2]=bf16rne(a.z); o[3]=bf16rne(a.w);
    o[4]=bf16rne(b.x); o[5]=bf16rne(b.y); o[6]=bf16rne(b.z); o[7]=bf16rne(b.w);
    return o;
}

__global__ __launch_bounds__(256)
void split_convert(const float* __restrict__ in, short* __restrict__ hi,
                   short* __restrict__ lo, int n4)
{
    const int i = blockIdx.x * 256 + threadIdx.x;
    if (i >= n4) return;
    float4 v = reinterpret_cast<const float4*>(in)[i];
    short4 h, l;
    split1(v.x, h.x, l.x);
    split1(v.y, h.y, l.y);
    split1(v.z, h.z, l.z);
    split1(v.w, h.w, l.w);
    reinterpret_cast<short4*>(hi)[i] = h;
    reinterpret_cast<short4*>(lo)[i] = l;
}

__global__ __launch_bounds__(256)
void concat_bias(const float* __restrict__ a, const float* __restrict__ b,
                 const float* __restrict__ c, float* __restrict__ o)
{
    const int i = blockIdx.x * 256 + threadIdx.x;
    o[i] = (i < 1024) ? a[i] : ((i < 2048) ? b[i - 1024] : c[i - 2048]);
}

// ---------------- split-bf16 MFMA GEMM (unchanged from round 2)
__global__ __launch_bounds__(256)
void gemm_split(const short* __restrict__ Ahi, const short* __restrict__ Alo,
                const short* __restrict__ Bhi, const short* __restrict__ Blo,
                const float* __restrict__ bias, float* __restrict__ C,
                int M, int N, int K)
{
    __shared__ short sAh[128*32];
    __shared__ short sAl[128*32];
    __shared__ short sBh[128*32];
    __shared__ short sBl[128*32];

    const int t = threadIdx.x;
    const int lane = t & 63, wid = t >> 6;
    const int wm = wid >> 1, wn = wid & 1;
    const int row0 = blockIdx.y * 128, col0 = blockIdx.x * 128;
    const int g = lane >> 4, r = lane & 15;
    const int sw = g ^ ((lane >> 2) & 3);
    const int srow = lane >> 2;
    const int sslot = lane & 3;

    f32x4 acc[4][4];
    #pragma unroll
    for (int mt = 0; mt < 4; ++mt)
        #pragma unroll
        for (int nt = 0; nt < 4; ++nt) acc[mt][nt] = (f32x4){0.f, 0.f, 0.f, 0.f};

    for (int k0 = 0; k0 < K; k0 += 32) {
        #pragma unroll
        for (int i = 0; i < 2; ++i) {
            const int rl = wid * 32 + i * 16 + srow;
            const int scol = k0 + ((sslot ^ ((rl >> 2) & 3)) << 3);
            const size_t ga = (size_t)(row0 + rl) * K + scol;
            const size_t gb = (size_t)(col0 + rl) * K + scol;
            const int ldso = (wid * 32 + i * 16) * 32;
            __builtin_amdgcn_global_load_lds(GLB_CAST(Ahi + ga), LDS_CAST(sAh + ldso), 16, 0, 0);
            __builtin_amdgcn_global_load_lds(GLB_CAST(Alo + ga), LDS_CAST(sAl + ldso), 16, 0, 0);
            __builtin_amdgcn_global_load_lds(GLB_CAST(Bhi + gb), LDS_CAST(sBh + ldso), 16, 0, 0);
            __builtin_amdgcn_global_load_lds(GLB_CAST(Blo + gb), LDS_CAST(sBl + ldso), 16, 0, 0);
        }
        __syncthreads();

        bf16x8 ah[4], al[4], bh[4], bl[4];
        #pragma unroll
        for (int mt = 0; mt < 4; ++mt) {
            const int row = wm * 64 + mt * 16 + r;
            ah[mt] = *reinterpret_cast<const bf16x8*>(sAh + row * 32 + sw * 8);
            al[mt] = *reinterpret_cast<const bf16x8*>(sAl + row * 32 + sw * 8);
        }
        #pragma unroll
        for (int nt = 0; nt < 4; ++nt) {
            const int row = wn * 64 + nt * 16 + r;
            bh[nt] = *reinterpret_cast<const bf16x8*>(sBh + row * 32 + sw * 8);
            bl[nt] = *reinterpret_cast<const bf16x8*>(sBl + row * 32 + sw * 8);
        }
        #pragma unroll
        for (int mt = 0; mt < 4; ++mt)
            #pragma unroll
            for (int nt = 0; nt < 4; ++nt) {
                acc[mt][nt] = __builtin_amdgcn_mfma_f32_16x16x32_bf16(ah[mt], bh[nt], acc[mt][nt], 0, 0, 0);
                acc[mt][nt] = __builtin_amdgcn_mfma_f32_16x16x32_bf16(ah[mt], bl[nt], acc[mt][nt], 0, 0, 0);
                acc[mt][nt] = __builtin_amdgcn_mfma_f32_16x16x32_bf16(al[mt], bh[nt], acc[mt][nt], 0, 0, 0);
            }
        __syncthreads();
    }

    #pragma unroll
    for (int nt = 0; nt < 4; ++nt) {
        const int col = col0 + wn * 64 + nt * 16 + r;
        const float bv = bias[col];
        #pragma unroll
        for (int mt = 0; mt < 4; ++mt) {
            #pragma unroll
            for (int e = 0; e < 4; ++e) {
                const int row = row0 + wm * 64 + mt * 16 + 4 * g + e;
                C[(size_t)row * N + col] = acc[mt][nt][e] + bv;
            }
        }
    }
}

// ---------------- importance / top-k (unchanged)
__global__ __launch_bounds__(256)
void importance_kernel(const float* __restrict__ h, const float* __restrict__ wi2,
                       const float* __restrict__ bi2, float* __restrict__ imp)
{
    const int wid = threadIdx.x >> 6, lane = threadIdx.x & 63;
    const int row = blockIdx.x * 4 + wid;
    const float* hr = h + (size_t)row * DH;
    float s = 0.f;
    #pragma unroll
    for (int i = 0; i < DH/64; ++i)
        s = fmaf(hr[lane + i*64], wi2[lane + i*64], s);
    #pragma unroll
    for (int off = 32; off; off >>= 1) s += __shfl_down(s, off);
    if (lane == 0) imp[row] = s + bi2[0];
}

__global__ __launch_bounds__(256)
void rank_kernel(const float* __restrict__ imp, int* __restrict__ flags)
{
    const int b = blockIdx.y;
    const int i = blockIdx.x * 256 + threadIdx.x;
    const float* bimp = imp + b * SS;
    const float v = bimp[i];
    int rank = 0;
    for (int j = 0; j < SS; ++j) {
        const float u = bimp[j];
        rank += (u > v) || ((u == v) && (j < i));
    }
    flags[b * SS + i] = (rank < KSEL) ? 1 : 0;
}

__global__ __launch_bounds__(256)
void compact_kernel(const int* __restrict__ flags, int* __restrict__ idxg)
{
    __shared__ int sscan[SS];
    __shared__ int sidx[KSEL];
    const int b = blockIdx.x, t = threadIdx.x;
    for (int i = t; i < SS; i += 256) sscan[i] = flags[b * SS + i];
    __syncthreads();
    for (int off = 1; off < SS; off <<= 1) {
        int vals[SS/256];
        #pragma unroll
        for (int c = 0; c < SS/256; ++c) {
            const int i = t + c * 256;
            int v = sscan[i];
            if (i >= off) v += sscan[i - off];
            vals[c] = v;
        }
        __syncthreads();
        #pragma unroll
        for (int c = 0; c < SS/256; ++c) sscan[t + c * 256] = vals[c];
        __syncthreads();
    }
    for (int i = t; i < SS; i += 256) {
        const int f = flags[b * SS + i];
        if (f) sidx[sscan[i] - 1] = i;
    }
    __syncthreads();
    for (int p = t; p < KPAD; p += 256)
        idxg[b * KPAD + p] = sidx[min(p, KSEL - 1)];
}

// ---------------- MFMA sparse flash attention
// block = (qtile 64, head, batch); 4 waves x 16 q-rows.
// K LDS: [64 keys][72] bf16 row-major. V LDS transposed: Vt[d][key ^ (8*(d>>4))].
// P LDS per-wave: Ps[q][k ^ (8*(q>>2))]. Q split hi/lo (2 MFMA per QK tile).
__global__ __launch_bounds__(256)
void attn_mfma(const float* __restrict__ QKV, const int* __restrict__ idxg,
               short* __restrict__ AOhi, short* __restrict__ AOlo)
{
    __shared__ short Ks[64*72];
    __shared__ short Vt[64*72];
    __shared__ short Ps[4][16*72];

    const int t = threadIdx.x;
    const int lane = t & 63, w = t >> 6;
    const int g = lane >> 4, r = lane & 15;
    const int qt = blockIdx.x, h = blockIdx.y, b = blockIdx.z;
    const int q0 = qt * 64;
    const int* bidx = idxg + b * KPAD;
    short* Psw = &Ps[w][0];

    // Q fragments, pre-scaled by 1/8, split hi/lo
    bf16x8 qh[2], ql[2];
    {
        const float* qrow = QKV + (size_t)(b * SS + q0 + w * 16 + r) * QKVS + h * HD;
        #pragma unroll
        for (int ch = 0; ch < 2; ++ch) {
            float4 f0 = *reinterpret_cast<const float4*>(&qrow[ch*32 + 8*g]);
            float4 f1 = *reinterpret_cast<const float4*>(&qrow[ch*32 + 8*g + 4]);
            float v[8] = {f0.x, f0.y, f0.z, f0.w, f1.x, f1.y, f1.z, f1.w};
            #pragma unroll
            for (int e = 0; e < 8; ++e) {
                short hh, ll;
                split1(v[e] * 0.125f, hh, ll);
                qh[ch][e] = hh; ql[ch][e] = ll;
            }
        }
    }

    f32x4 oacc[4];
    #pragma unroll
    for (int dt = 0; dt < 4; ++dt) oacc[dt] = (f32x4){0.f, 0.f, 0.f, 0.f};
    float mrun[4] = {-INFINITY, -INFINITY, -INFINITY, -INFINITY};
    float lrun[4] = {0.f, 0.f, 0.f, 0.f};

    const int srow = t >> 2;   // key slot 0..63
    const int sq4  = t & 3;    // 16-element quarter

    for (int c = 0; c < NCH; ++c) {
        __syncthreads();
        // ---- stage K row-major + V transposed (bf16)
        {
            const int krow = bidx[c * 64 + srow];
            const float* kb = QKV + (size_t)(b * SS + krow) * QKVS + 1024 + h * HD + sq4 * 16;
            float4 k0 = *reinterpret_cast<const float4*>(kb);
            float4 k1 = *reinterpret_cast<const float4*>(kb + 4);
            float4 k2 = *reinterpret_cast<const float4*>(kb + 8);
            float4 k3 = *reinterpret_cast<const float4*>(kb + 12);
            const float* vb = kb + 1024;
            float4 v0 = *reinterpret_cast<const float4*>(vb);
            float4 v1 = *reinterpret_cast<const float4*>(vb + 4);
            float4 v2 = *reinterpret_cast<const float4*>(vb + 8);
            float4 v3 = *reinterpret_cast<const float4*>(vb + 12);
            *reinterpret_cast<bf16x8*>(&Ks[srow*72 + sq4*16])     = pack8(k0, k1);
            *reinterpret_cast<bf16x8*>(&Ks[srow*72 + sq4*16 + 8]) = pack8(k2, k3);
            float vv[16] = {v0.x,v0.y,v0.z,v0.w, v1.x,v1.y,v1.z,v1.w,
                            v2.x,v2.y,v2.z,v2.w, v3.x,v3.y,v3.z,v3.w};
            const int vcol = srow ^ (8 * sq4);   // swizzle: (d>>4)&3 == sq4
            #pragma unroll
            for (int j = 0; j < 16; ++j)
                Vt[(sq4*16 + j)*72 + vcol] = bf16rne(vv[j]);
        }
        __syncthreads();

        // ---- QK^T (Q split hi/lo, K bf16)
        f32x4 sa[4];
        #pragma unroll
        for (int kt = 0; kt < 4; ++kt) {
            bf16x8 kf0 = *reinterpret_cast<const bf16x8*>(&Ks[(kt*16 + r)*72 + 8*g]);
            bf16x8 kf1 = *reinterpret_cast<const bf16x8*>(&Ks[(kt*16 + r)*72 + 32 + 8*g]);
            f32x4 s = (f32x4){0.f, 0.f, 0.f, 0.f};
            s = __builtin_amdgcn_mfma_f32_16x16x32_bf16(qh[0], kf0, s, 0, 0, 0);
            s = __builtin_amdgcn_mfma_f32_16x16x32_bf16(ql[0], kf0, s, 0, 0, 0);
            s = __builtin_amdgcn_mfma_f32_16x16x32_bf16(qh[1], kf1, s, 0, 0, 0);
            s = __builtin_amdgcn_mfma_f32_16x16x32_bf16(ql[1], kf1, s, 0, 0, 0);
            sa[kt] = s;
        }
        if (c == NCH - 1) {
            #pragma unroll
            for (int kt = 0; kt < 4; ++kt)
                if (c*64 + kt*16 + r >= KSEL)
                    sa[kt] = (f32x4){-INFINITY, -INFINITY, -INFINITY, -INFINITY};
        }

        // ---- online softmax (rows q = 4g+e; reduce over 16-lane key groups)
        float p[4][4], scl[4];
        #pragma unroll
        for (int e = 0; e < 4; ++e) {
            float mx = fmaxf(fmaxf(sa[0][e], sa[1][e]), fmaxf(sa[2][e], sa[3][e]));
            #pragma unroll
            for (int off = 1; off < 16; off <<= 1) mx = fmaxf(mx, __shfl_xor(mx, off));
            const float mnew = fmaxf(mrun[e], mx);
            scl[e] = __expf(mrun[e] - mnew);
            float s0 = 0.f;
            #pragma unroll
            for (int kt = 0; kt < 4; ++kt) { p[kt][e] = __expf(sa[kt][e] - mnew); s0 += p[kt][e]; }
            #pragma unroll
            for (int off = 1; off < 16; off <<= 1) s0 += __shfl_xor(s0, off);
            lrun[e] = lrun[e] * scl[e] + s0;
            mrun[e] = mnew;
        }
        #pragma unroll
        for (int dt = 0; dt < 4; ++dt)
            #pragma unroll
            for (int e = 0; e < 4; ++e) oacc[dt][e] *= scl[e];

        // ---- P -> bf16 to per-wave LDS (swizzled transpose)
        #pragma unroll
        for (int kt = 0; kt < 4; ++kt)
            #pragma unroll
            for (int e = 0; e < 4; ++e)
                Psw[(4*g + e)*72 + ((kt*16 + r) ^ (8*g))] = bf16rne(p[kt][e]);

        // ---- PV
        #pragma unroll
        for (int kc = 0; kc < 2; ++kc) {
            bf16x8 pf = *reinterpret_cast<const bf16x8*>(&Psw[r*72 + kc*32 + 8*(g ^ (r >> 2))]);
            #pragma unroll
            for (int dt = 0; dt < 4; ++dt) {
                bf16x8 vf = *reinterpret_cast<const bf16x8*>(&Vt[(dt*16 + r)*72 + kc*32 + 8*(g ^ dt)]);
                oacc[dt] = __builtin_amdgcn_mfma_f32_16x16x32_bf16(pf, vf, oacc[dt], 0, 0, 0);
            }
        }
    }

    // ---- epilogue: normalize, split hi/lo, store
    #pragma unroll
    for (int dt = 0; dt < 4; ++dt)
        #pragma unroll
        for (int e = 0; e < 4; ++e) {
            const float o = oacc[dt][e] / lrun[e];
            short hh, ll;
            split1(o, hh, ll);
            const size_t a = (size_t)(b * SS + q0 + w*16 + 4*g + e) * DD + h * HD + dt*16 + r;
            AOhi[a] = hh; AOlo[a] = ll;
        }
}

extern "C" void kernel_launch(void* const* d_in, const int* in_sizes, int n_in,
                              void* d_out, int out_size, void* d_ws, size_t ws_size,
                              hipStream_t stream)
{
    const float* x   = (const float*)d_in[0];
    const float* wq  = (const float*)d_in[1];
    const float* bq  = (const float*)d_in[2];
    const float* wk  = (const float*)d_in[3];
    const float* bk  = (const float*)d_in[4];
    const float* wv  = (const float*)d_in[5];
    const float* bv  = (const float*)d_in[6];
    const float* wo  = (const float*)d_in[7];
    const float* bo  = (const float*)d_in[8];
    const float* wi1 = (const float*)d_in[9];
    const float* bi1 = (const float*)d_in[10];
    const float* wi2 = (const float*)d_in[11];
    const float* bi2 = (const float*)d_in[12];
    float* out = (float*)d_out;

    const size_t MB = 1ull << 20;
    char* W = (char*)d_ws;
    short* x_hi  = (short*)(W + 0);          // 16 MB
    short* x_lo  = (short*)(W + 16*MB);      // 16 MB
    float* QKV   = (float*)(W + 32*MB);      // 96 MB
    short* Bq_hi = (short*)(W + 128*MB);     // 6 MB
    short* Bq_lo = (short*)(W + 134*MB);     // 6 MB
    short* wo_hi = (short*)(W + 140*MB);     // 2 MB
    short* wo_lo = (short*)(W + 142*MB);     // 2 MB
    float* Hw    = (float*)(W + 144*MB);     // 16 MB
    float* bqkv  = (float*)(W + 160*MB);
    float* imp   = (float*)(W + 160*MB + 64*1024);
    int*   flags = (int*)(W + 160*MB + 128*1024);
    int*   idxg  = (int*)(W + 160*MB + 192*1024);
    // attn output hi/lo overwrite x_hi/x_lo (dead after QKV projection)
    short* AO_hi = x_hi;
    short* AO_lo = x_lo;

    const size_t NM = (size_t)MTOT * DD;

    // 0. splits + fused bias
    split_convert<<<(NM/4 + 255)/256, 256, 0, stream>>>(x, x_hi, x_lo, NM/4);
    split_convert<<<(DD*DD/4 + 255)/256, 256, 0, stream>>>(wq, Bq_hi,           Bq_lo,           DD*DD/4);
    split_convert<<<(DD*DD/4 + 255)/256, 256, 0, stream>>>(wk, Bq_hi + DD*DD,   Bq_lo + DD*DD,   DD*DD/4);
    split_convert<<<(DD*DD/4 + 255)/256, 256, 0, stream>>>(wv, Bq_hi + 2*DD*DD, Bq_lo + 2*DD*DD, DD*DD/4);
    split_convert<<<(DD*DD/4 + 255)/256, 256, 0, stream>>>(wo, wo_hi, wo_lo, DD*DD/4);
    concat_bias<<<QKVS/256, 256, 0, stream>>>(bq, bk, bv, bqkv);

    // 1-3. indexer (exact fp32 path for top-k stability)
    gemm_nt<true><<<dim3(DH/BN, MTOT/BM), 256, 0, stream>>>(x, wi1, bi1, Hw, MTOT, DH, DD);
    importance_kernel<<<MTOT/4, 256, 0, stream>>>(Hw, wi2, bi2, imp);
    rank_kernel<<<dim3(SS/256, BB), 256, 0, stream>>>(imp, flags);
    compact_kernel<<<BB, 256, 0, stream>>>(flags, idxg);

    // 4. fused QKV projection
    gemm_split<<<dim3(QKVS/128, MTOT/128), 256, 0, stream>>>(
        x_hi, x_lo, Bq_hi, Bq_lo, bqkv, QKV, MTOT, QKVS, DD);

    // 5. MFMA sparse flash attention -> bf16 hi/lo directly
    attn_mfma<<<dim3(SS/64, HHD, BB), 256, 0, stream>>>(QKV, idxg, AO_hi, AO_lo);

    // 6. output projection
    gemm_split<<<dim3(DD/128, MTOT/128), 256, 0, stream>>>(
        AO_hi, AO_lo, wo_hi, wo_lo, bo, out, MTOT, DD, DD);
}

// Round 4
// 481.426 us; speedup vs baseline: 3.6837x; 1.2438x over previous
//
#include <hip/hip_runtime.h>
#include <math.h>

#define BB 4
#define SS 2048
#define DD 1024
#define HHD 16      // heads
#define HD 64       // head dim
#define DH 512      // indexer hidden
#define KSEL 614    // top-k count
#define KPAD 640    // padded to multiple of 64
#define MTOT (BB*SS)
#define QKVS 3072   // fused QKV row stride
#define NCH (KPAD/64)

typedef __attribute__((ext_vector_type(8))) short bf16x8;
typedef __attribute__((ext_vector_type(4))) float f32x4;

#define LDS_CAST(p) ((__attribute__((address_space(3))) void*)(p))
#define GLB_CAST(p) ((const __attribute__((address_space(1))) void*)(p))

// ---------------- fp32 -> bf16 helpers (RNE)
__device__ inline short bf16rne(float v)
{
    unsigned u = __builtin_bit_cast(unsigned, v);
    return (short)((u + 0x7FFFu + ((u >> 16) & 1u)) >> 16);
}

__device__ inline void split1(float v, short& h, short& l)
{
    unsigned u = __builtin_bit_cast(unsigned, v);
    unsigned hr = (u + 0x7FFFu + ((u >> 16) & 1u)) >> 16;
    h = (short)hr;
    float hf = __builtin_bit_cast(float, hr << 16);
    float res = v - hf;
    unsigned u2 = __builtin_bit_cast(unsigned, res);
    unsigned lr = (u2 + 0x7FFFu + ((u2 >> 16) & 1u)) >> 16;
    l = (short)lr;
}

__device__ inline bf16x8 pack8(float4 a, float4 b)
{
    bf16x8 o;
    o[0]=bf16rne(a.x); o[1]=bf16rne(a.y); o[2]=bf16rne(a.z); o[3]=bf16rne(a.w);
    o[4]=bf16rne(b.x); o[5]=bf16rne(b.y); o[6]=bf16rne(b.z); o[7]=bf16rne(b.w);
    return o;
}

__global__ __launch_bounds__(256)
void split_convert(const float* __restrict__ in, short* __restrict__ hi,
                   short* __restrict__ lo, int n4)
{
    const int i = blockIdx.x * 256 + threadIdx.x;
    if (i >= n4) return;
    float4 v = reinterpret_cast<const float4*>(in)[i];
    short4 h, l;
    split1(v.x, h.x, l.x);
    split1(v.y, h.y, l.y);
    split1(v.z, h.z, l.z);
    split1(v.w, h.w, l.w);
    reinterpret_cast<short4*>(hi)[i] = h;
    reinterpret_cast<short4*>(lo)[i] = l;
}

__global__ __launch_bounds__(256)
void concat_bias(const float* __restrict__ a, const float* __restrict__ b,
                 const float* __restrict__ c, float* __restrict__ o)
{
    const int i = blockIdx.x * 256 + threadIdx.x;
    o[i] = (i < 1024) ? a[i] : ((i < 2048) ? b[i - 1024] : c[i - 2048]);
}

// ---------------- split-bf16 MFMA GEMM: C[M,N] = (Ahi+Alo)[M,K] @ (Bhi+Blo)[N,K]^T + bias
// 128x128 tile, BK=32, 4 waves (2x2 of 64x64). TERM4 adds lo*lo (top-k-critical path).
template<bool RELU, bool TERM4>
__global__ __launch_bounds__(256)
void gemm_split(const short* __restrict__ Ahi, const short* __restrict__ Alo,
                const short* __restrict__ Bhi, const short* __restrict__ Blo,
                const float* __restrict__ bias, float* __restrict__ C,
                int M, int N, int K)
{
    __shared__ short sAh[128*32];
    __shared__ short sAl[128*32];
    __shared__ short sBh[128*32];
    __shared__ short sBl[128*32];

    const int t = threadIdx.x;
    const int lane = t & 63, wid = t >> 6;
    const int wm = wid >> 1, wn = wid & 1;
    const int row0 = blockIdx.y * 128, col0 = blockIdx.x * 128;
    const int g = lane >> 4, r = lane & 15;
    const int sw = g ^ ((lane >> 2) & 3);
    const int srow = lane >> 2;
    const int sslot = lane & 3;

    f32x4 acc[4][4];
    #pragma unroll
    for (int mt = 0; mt < 4; ++mt)
        #pragma unroll
        for (int nt = 0; nt < 4; ++nt) acc[mt][nt] = (f32x4){0.f, 0.f, 0.f, 0.f};

    for (int k0 = 0; k0 < K; k0 += 32) {
        #pragma unroll
        for (int i = 0; i < 2; ++i) {
            const int rl = wid * 32 + i * 16 + srow;
            const int scol = k0 + ((sslot ^ ((rl >> 2) & 3)) << 3);
            const size_t ga = (size_t)(row0 + rl) * K + scol;
            const size_t gb = (size_t)(col0 + rl) * K + scol;
            const int ldso = (wid * 32 + i * 16) * 32;
            __builtin_amdgcn_global_load_lds(GLB_CAST(Ahi + ga), LDS_CAST(sAh + ldso), 16, 0, 0);
            __builtin_amdgcn_global_load_lds(GLB_CAST(Alo + ga), LDS_CAST(sAl + ldso), 16, 0, 0);
            __builtin_amdgcn_global_load_lds(GLB_CAST(Bhi + gb), LDS_CAST(sBh + ldso), 16, 0, 0);
            __builtin_amdgcn_global_load_lds(GLB_CAST(Blo + gb), LDS_CAST(sBl + ldso), 16, 0, 0);
        }
        __syncthreads();

        bf16x8 ah[4], al[4], bh[4], bl[4];
        #pragma unroll
        for (int mt = 0; mt < 4; ++mt) {
            const int row = wm * 64 + mt * 16 + r;
            ah[mt] = *reinterpret_cast<const bf16x8*>(sAh + row * 32 + sw * 8);
            al[mt] = *reinterpret_cast<const bf16x8*>(sAl + row * 32 + sw * 8);
        }
        #pragma unroll
        for (int nt = 0; nt < 4; ++nt) {
            const int row = wn * 64 + nt * 16 + r;
            bh[nt] = *reinterpret_cast<const bf16x8*>(sBh + row * 32 + sw * 8);
            bl[nt] = *reinterpret_cast<const bf16x8*>(sBl + row * 32 + sw * 8);
        }
        #pragma unroll
        for (int mt = 0; mt < 4; ++mt)
            #pragma unroll
            for (int nt = 0; nt < 4; ++nt) {
                acc[mt][nt] = __builtin_amdgcn_mfma_f32_16x16x32_bf16(ah[mt], bh[nt], acc[mt][nt], 0, 0, 0);
                acc[mt][nt] = __builtin_amdgcn_mfma_f32_16x16x32_bf16(ah[mt], bl[nt], acc[mt][nt], 0, 0, 0);
                acc[mt][nt] = __builtin_amdgcn_mfma_f32_16x16x32_bf16(al[mt], bh[nt], acc[mt][nt], 0, 0, 0);
                if (TERM4)
                    acc[mt][nt] = __builtin_amdgcn_mfma_f32_16x16x32_bf16(al[mt], bl[nt], acc[mt][nt], 0, 0, 0);
            }
        __syncthreads();
    }

    #pragma unroll
    for (int nt = 0; nt < 4; ++nt) {
        const int col = col0 + wn * 64 + nt * 16 + r;
        const float bv = bias[col];
        #pragma unroll
        for (int mt = 0; mt < 4; ++mt) {
            #pragma unroll
            for (int e = 0; e < 4; ++e) {
                const int row = row0 + wm * 64 + mt * 16 + 4 * g + e;
                float v = acc[mt][nt][e] + bv;
                if (RELU) v = fmaxf(v, 0.f);
                C[(size_t)row * N + col] = v;
            }
        }
    }
}

// ---------------- importance / top-k
__global__ __launch_bounds__(256)
void importance_kernel(const float* __restrict__ h, const float* __restrict__ wi2,
                       const float* __restrict__ bi2, float* __restrict__ imp)
{
    const int wid = threadIdx.x >> 6, lane = threadIdx.x & 63;
    const int row = blockIdx.x * 4 + wid;
    const float* hr = h + (size_t)row * DH;
    float s = 0.f;
    #pragma unroll
    for (int i = 0; i < DH/64; ++i)
        s = fmaf(hr[lane + i*64], wi2[lane + i*64], s);
    #pragma unroll
    for (int off = 32; off; off >>= 1) s += __shfl_down(s, off);
    if (lane == 0) imp[row] = s + bi2[0];
}

__global__ __launch_bounds__(256)
void rank_kernel(const float* __restrict__ imp, int* __restrict__ flags)
{
    const int b = blockIdx.y;
    const int i = blockIdx.x * 256 + threadIdx.x;
    const float* bimp = imp + b * SS;
    const float v = bimp[i];
    int rank = 0;
    for (int j = 0; j < SS; ++j) {
        const float u = bimp[j];
        rank += (u > v) || ((u == v) && (j < i));
    }
    flags[b * SS + i] = (rank < KSEL) ? 1 : 0;
}

__global__ __launch_bounds__(256)
void compact_kernel(const int* __restrict__ flags, int* __restrict__ idxg)
{
    __shared__ int sscan[SS];
    __shared__ int sidx[KSEL];
    const int b = blockIdx.x, t = threadIdx.x;
    for (int i = t; i < SS; i += 256) sscan[i] = flags[b * SS + i];
    __syncthreads();
    for (int off = 1; off < SS; off <<= 1) {
        int vals[SS/256];
        #pragma unroll
        for (int c = 0; c < SS/256; ++c) {
            const int i = t + c * 256;
            int v = sscan[i];
            if (i >= off) v += sscan[i - off];
            vals[c] = v;
        }
        __syncthreads();
        #pragma unroll
        for (int c = 0; c < SS/256; ++c) sscan[t + c * 256] = vals[c];
        __syncthreads();
    }
    for (int i = t; i < SS; i += 256) {
        const int f = flags[b * SS + i];
        if (f) sidx[sscan[i] - 1] = i;
    }
    __syncthreads();
    for (int p = t; p < KPAD; p += 256)
        idxg[b * KPAD + p] = sidx[min(p, KSEL - 1)];
}

// ---------------- MFMA sparse flash attention (unchanged from round 3)
__global__ __launch_bounds__(256)
void attn_mfma(const float* __restrict__ QKV, const int* __restrict__ idxg,
               short* __restrict__ AOhi, short* __restrict__ AOlo)
{
    __shared__ short Ks[64*72];
    __shared__ short Vt[64*72];
    __shared__ short Ps[4][16*72];

    const int t = threadIdx.x;
    const int lane = t & 63, w = t >> 6;
    const int g = lane >> 4, r = lane & 15;
    const int qt = blockIdx.x, h = blockIdx.y, b = blockIdx.z;
    const int q0 = qt * 64;
    const int* bidx = idxg + b * KPAD;
    short* Psw = &Ps[w][0];

    bf16x8 qh[2], ql[2];
    {
        const float* qrow = QKV + (size_t)(b * SS + q0 + w * 16 + r) * QKVS + h * HD;
        #pragma unroll
        for (int ch = 0; ch < 2; ++ch) {
            float4 f0 = *reinterpret_cast<const float4*>(&qrow[ch*32 + 8*g]);
            float4 f1 = *reinterpret_cast<const float4*>(&qrow[ch*32 + 8*g + 4]);
            float v[8] = {f0.x, f0.y, f0.z, f0.w, f1.x, f1.y, f1.z, f1.w};
            #pragma unroll
            for (int e = 0; e < 8; ++e) {
                short hh, ll;
                split1(v[e] * 0.125f, hh, ll);
                qh[ch][e] = hh; ql[ch][e] = ll;
            }
        }
    }

    f32x4 oacc[4];
    #pragma unroll
    for (int dt = 0; dt < 4; ++dt) oacc[dt] = (f32x4){0.f, 0.f, 0.f, 0.f};
    float mrun[4] = {-INFINITY, -INFINITY, -INFINITY, -INFINITY};
    float lrun[4] = {0.f, 0.f, 0.f, 0.f};

    const int srow = t >> 2;
    const int sq4  = t & 3;

    for (int c = 0; c < NCH; ++c) {
        __syncthreads();
        {
            const int krow = bidx[c * 64 + srow];
            const float* kb = QKV + (size_t)(b * SS + krow) * QKVS + 1024 + h * HD + sq4 * 16;
            float4 k0 = *reinterpret_cast<const float4*>(kb);
            float4 k1 = *reinterpret_cast<const float4*>(kb + 4);
            float4 k2 = *reinterpret_cast<const float4*>(kb + 8);
            float4 k3 = *reinterpret_cast<const float4*>(kb + 12);
            const float* vb = kb + 1024;
            float4 v0 = *reinterpret_cast<const float4*>(vb);
            float4 v1 = *reinterpret_cast<const float4*>(vb + 4);
            float4 v2 = *reinterpret_cast<const float4*>(vb + 8);
            float4 v3 = *reinterpret_cast<const float4*>(vb + 12);
            *reinterpret_cast<bf16x8*>(&Ks[srow*72 + sq4*16])     = pack8(k0, k1);
            *reinterpret_cast<bf16x8*>(&Ks[srow*72 + sq4*16 + 8]) = pack8(k2, k3);
            float vv[16] = {v0.x,v0.y,v0.z,v0.w, v1.x,v1.y,v1.z,v1.w,
                            v2.x,v2.y,v2.z,v2.w, v3.x,v3.y,v3.z,v3.w};
            const int vcol = srow ^ (8 * sq4);
            #pragma unroll
            for (int j = 0; j < 16; ++j)
                Vt[(sq4*16 + j)*72 + vcol] = bf16rne(vv[j]);
        }
        __syncthreads();

        f32x4 sa[4];
        #pragma unroll
        for (int kt = 0; kt < 4; ++kt) {
            bf16x8 kf0 = *reinterpret_cast<const bf16x8*>(&Ks[(kt*16 + r)*72 + 8*g]);
            bf16x8 kf1 = *reinterpret_cast<const bf16x8*>(&Ks[(kt*16 + r)*72 + 32 + 8*g]);
            f32x4 s = (f32x4){0.f, 0.f, 0.f, 0.f};
            s = __builtin_amdgcn_mfma_f32_16x16x32_bf16(qh[0], kf0, s, 0, 0, 0);
            s = __builtin_amdgcn_mfma_f32_16x16x32_bf16(ql[0], kf0, s, 0, 0, 0);
            s = __builtin_amdgcn_mfma_f32_16x16x32_bf16(qh[1], kf1, s, 0, 0, 0);
            s = __builtin_amdgcn_mfma_f32_16x16x32_bf16(ql[1], kf1, s, 0, 0, 0);
            sa[kt] = s;
        }
        if (c == NCH - 1) {
            #pragma unroll
            for (int kt = 0; kt < 4; ++kt)
                if (c*64 + kt*16 + r >= KSEL)
                    sa[kt] = (f32x4){-INFINITY, -INFINITY, -INFINITY, -INFINITY};
        }

        float p[4][4], scl[4];
        #pragma unroll
        for (int e = 0; e < 4; ++e) {
            float mx = fmaxf(fmaxf(sa[0][e], sa[1][e]), fmaxf(sa[2][e], sa[3][e]));
            #pragma unroll
            for (int off = 1; off < 16; off <<= 1) mx = fmaxf(mx, __shfl_xor(mx, off));
            const float mnew = fmaxf(mrun[e], mx);
            scl[e] = __expf(mrun[e] - mnew);
            float s0 = 0.f;
            #pragma unroll
            for (int kt = 0; kt < 4; ++kt) { p[kt][e] = __expf(sa[kt][e] - mnew); s0 += p[kt][e]; }
            #pragma unroll
            for (int off = 1; off < 16; off <<= 1) s0 += __shfl_xor(s0, off);
            lrun[e] = lrun[e] * scl[e] + s0;
            mrun[e] = mnew;
        }
        #pragma unroll
        for (int dt = 0; dt < 4; ++dt)
            #pragma unroll
            for (int e = 0; e < 4; ++e) oacc[dt][e] *= scl[e];

        #pragma unroll
        for (int kt = 0; kt < 4; ++kt)
            #pragma unroll
            for (int e = 0; e < 4; ++e)
                Psw[(4*g + e)*72 + ((kt*16 + r) ^ (8*g))] = bf16rne(p[kt][e]);

        #pragma unroll
        for (int kc = 0; kc < 2; ++kc) {
            bf16x8 pf = *reinterpret_cast<const bf16x8*>(&Psw[r*72 + kc*32 + 8*(g ^ (r >> 2))]);
            #pragma unroll
            for (int dt = 0; dt < 4; ++dt) {
                bf16x8 vf = *reinterpret_cast<const bf16x8*>(&Vt[(dt*16 + r)*72 + kc*32 + 8*(g ^ dt)]);
                oacc[dt] = __builtin_amdgcn_mfma_f32_16x16x32_bf16(pf, vf, oacc[dt], 0, 0, 0);
            }
        }
    }

    #pragma unroll
    for (int dt = 0; dt < 4; ++dt)
        #pragma unroll
        for (int e = 0; e < 4; ++e) {
            const float o = oacc[dt][e] / lrun[e];
            short hh, ll;
            split1(o, hh, ll);
            const size_t a = (size_t)(b * SS + q0 + w*16 + 4*g + e) * DD + h * HD + dt*16 + r;
            AOhi[a] = hh; AOlo[a] = ll;
        }
}

extern "C" void kernel_launch(void* const* d_in, const int* in_sizes, int n_in,
                              void* d_out, int out_size, void* d_ws, size_t ws_size,
                              hipStream_t stream)
{
    const float* x   = (const float*)d_in[0];
    const float* wq  = (const float*)d_in[1];
    const float* bq  = (const float*)d_in[2];
    const float* wk  = (const float*)d_in[3];
    const float* bk  = (const float*)d_in[4];
    const float* wv  = (const float*)d_in[5];
    const float* bv  = (const float*)d_in[6];
    const float* wo  = (const float*)d_in[7];
    const float* bo  = (const float*)d_in[8];
    const float* wi1 = (const float*)d_in[9];
    const float* bi1 = (const float*)d_in[10];
    const float* wi2 = (const float*)d_in[11];
    const float* bi2 = (const float*)d_in[12];
    float* out = (float*)d_out;

    const size_t MB = 1ull << 20;
    char* W = (char*)d_ws;
    short* x_hi  = (short*)(W + 0);          // 16 MB
    short* x_lo  = (short*)(W + 16*MB);      // 16 MB
    float* QKV   = (float*)(W + 32*MB);      // 96 MB
    short* Bq_hi = (short*)(W + 128*MB);     // 6 MB
    short* Bq_lo = (short*)(W + 134*MB);     // 6 MB
    short* wo_hi = (short*)(W + 140*MB);     // 2 MB
    short* wo_lo = (short*)(W + 142*MB);     // 2 MB
    float* Hw    = (float*)(W + 144*MB);     // 16 MB
    float* bqkv  = (float*)(W + 160*MB);
    float* imp   = (float*)(W + 160*MB + 64*1024);
    int*   flags = (int*)(W + 160*MB + 128*1024);
    int*   idxg  = (int*)(W + 160*MB + 192*1024);
    // wi1 hi/lo live inside the (not yet written) QKV region: consumed by the
    // indexer GEMM before the QKV projection overwrites this region.
    short* Wi_hi = (short*)(W + 32*MB);      // 1 MB
    short* Wi_lo = (short*)(W + 33*MB);      // 1 MB
    // attn output hi/lo overwrite x_hi/x_lo (dead after QKV projection)
    short* AO_hi = x_hi;
    short* AO_lo = x_lo;

    const size_t NM = (size_t)MTOT * DD;

    // 0. splits + fused bias
    split_convert<<<(NM/4 + 255)/256, 256, 0, stream>>>(x, x_hi, x_lo, NM/4);
    split_convert<<<(DD*DD/4 + 255)/256, 256, 0, stream>>>(wq, Bq_hi,           Bq_lo,           DD*DD/4);
    split_convert<<<(DD*DD/4 + 255)/256, 256, 0, stream>>>(wk, Bq_hi + DD*DD,   Bq_lo + DD*DD,   DD*DD/4);
    split_convert<<<(DD*DD/4 + 255)/256, 256, 0, stream>>>(wv, Bq_hi + 2*DD*DD, Bq_lo + 2*DD*DD, DD*DD/4);
    split_convert<<<(DD*DD/4 + 255)/256, 256, 0, stream>>>(wo, wo_hi, wo_lo, DD*DD/4);
    split_convert<<<(DH*DD/4 + 255)/256, 256, 0, stream>>>(wi1, Wi_hi, Wi_lo, DH*DD/4);
    concat_bias<<<QKVS/256, 256, 0, stream>>>(bq, bk, bv, bqkv);

    // 1. indexer h = relu(x @ wi1^T + bi1)  -- 4-term split-bf16 MFMA (top-k critical)
    gemm_split<true, true><<<dim3(DH/128, MTOT/128), 256, 0, stream>>>(
        x_hi, x_lo, Wi_hi, Wi_lo, bi1, Hw, MTOT, DH, DD);
    // 2-3. importance + top-k
    importance_kernel<<<MTOT/4, 256, 0, stream>>>(Hw, wi2, bi2, imp);
    rank_kernel<<<dim3(SS/256, BB), 256, 0, stream>>>(imp, flags);
    compact_kernel<<<BB, 256, 0, stream>>>(flags, idxg);

    // 4. fused QKV projection (3-term; overwrites Wi_hi/Wi_lo region)
    gemm_split<false, false><<<dim3(QKVS/128, MTOT/128), 256, 0, stream>>>(
        x_hi, x_lo, Bq_hi, Bq_lo, bqkv, QKV, MTOT, QKVS, DD);

    // 5. MFMA sparse flash attention -> bf16 hi/lo directly
    attn_mfma<<<dim3(SS/64, HHD, BB), 256, 0, stream>>>(QKV, idxg, AO_hi, AO_lo);

    // 6. output projection
    gemm_split<false, false><<<dim3(DD/128, MTOT/128), 256, 0, stream>>>(
        AO_hi, AO_lo, wo_hi, wo_lo, bo, out, MTOT, DD, DD);
}

// Round 5
// 428.983 us; speedup vs baseline: 4.1341x; 1.1223x over previous
//
#include <hip/hip_runtime.h>
#include <math.h>

#define BB 4
#define SS 2048
#define DD 1024
#define HHD 16      // heads
#define HD 64       // head dim
#define DH 512      // indexer hidden
#define KSEL 614    // top-k count
#define KPAD 640    // padded to multiple of 64
#define MTOT (BB*SS)
#define QKVS 3072   // fused QKV row stride
#define NCH (KPAD/64)

typedef __attribute__((ext_vector_type(8))) short bf16x8;
typedef __attribute__((ext_vector_type(4))) float f32x4;

#define LDS_CAST(p) ((__attribute__((address_space(3))) void*)(p))
#define GLB_CAST(p) ((const __attribute__((address_space(1))) void*)(p))

// ---------------- fp32 -> bf16 helpers (RNE)
__device__ inline short bf16rne(float v)
{
    unsigned u = __builtin_bit_cast(unsigned, v);
    return (short)((u + 0x7FFFu + ((u >> 16) & 1u)) >> 16);
}

__device__ inline void split1(float v, short& h, short& l)
{
    unsigned u = __builtin_bit_cast(unsigned, v);
    unsigned hr = (u + 0x7FFFu + ((u >> 16) & 1u)) >> 16;
    h = (short)hr;
    float hf = __builtin_bit_cast(float, hr << 16);
    float res = v - hf;
    unsigned u2 = __builtin_bit_cast(unsigned, res);
    unsigned lr = (u2 + 0x7FFFu + ((u2 >> 16) & 1u)) >> 16;
    l = (short)lr;
}

__device__ inline bf16x8 pack8(float4 a, float4 b)
{
    bf16x8 o;
    o[0]=bf16rne(a.x); o[1]=bf16rne(a.y); o[2]=bf16rne(a.z); o[3]=bf16rne(a.w);
    o[4]=bf16rne(b.x); o[5]=bf16rne(b.y); o[6]=bf16rne(b.z); o[7]=bf16rne(b.w);
    return o;
}

__global__ __launch_bounds__(256)
void split_convert(const float* __restrict__ in, short* __restrict__ hi,
                   short* __restrict__ lo, int n4)
{
    const int i = blockIdx.x * 256 + threadIdx.x;
    if (i >= n4) return;
    float4 v = reinterpret_cast<const float4*>(in)[i];
    short4 h, l;
    split1(v.x, h.x, l.x);
    split1(v.y, h.y, l.y);
    split1(v.z, h.z, l.z);
    split1(v.w, h.w, l.w);
    reinterpret_cast<short4*>(hi)[i] = h;
    reinterpret_cast<short4*>(lo)[i] = l;
}

__global__ __launch_bounds__(256)
void concat_bias(const float* __restrict__ a, const float* __restrict__ b,
                 float* __restrict__ o)
{
    const int i = blockIdx.x * 256 + threadIdx.x;   // 2048
    o[i] = (i < 1024) ? a[i] : b[i - 1024];
}

// ---------------- plain bf16 MFMA GEMM: C[M,N] = Ahi @ Bhi^T + bias  (m97 structure)
// 128x128 tile, BK=32, 4 waves (2x2 of 64x64). For QK projection (softmax-damped precision).
__global__ __launch_bounds__(256)
void gemm_bf16(const short* __restrict__ Ahi, const short* __restrict__ Bhi,
               const float* __restrict__ bias, float* __restrict__ C,
               int M, int N, int K, int ldc)
{
    __shared__ short sAh[128*32];
    __shared__ short sBh[128*32];

    const int t = threadIdx.x;
    const int lane = t & 63, wid = t >> 6;
    const int wm = wid >> 1, wn = wid & 1;
    const int row0 = blockIdx.y * 128, col0 = blockIdx.x * 128;
    const int g = lane >> 4, r = lane & 15;
    const int sw = g ^ ((lane >> 2) & 3);
    const int srow = lane >> 2;
    const int sslot = lane & 3;

    f32x4 acc[4][4];
    #pragma unroll
    for (int mt = 0; mt < 4; ++mt)
        #pragma unroll
        for (int nt = 0; nt < 4; ++nt) acc[mt][nt] = (f32x4){0.f, 0.f, 0.f, 0.f};

    for (int k0 = 0; k0 < K; k0 += 32) {
        #pragma unroll
        for (int i = 0; i < 2; ++i) {
            const int rl = wid * 32 + i * 16 + srow;
            const int scol = k0 + ((sslot ^ ((rl >> 2) & 3)) << 3);
            const size_t ga = (size_t)(row0 + rl) * K + scol;
            const size_t gb = (size_t)(col0 + rl) * K + scol;
            const int ldso = (wid * 32 + i * 16) * 32;
            __builtin_amdgcn_global_load_lds(GLB_CAST(Ahi + ga), LDS_CAST(sAh + ldso), 16, 0, 0);
            __builtin_amdgcn_global_load_lds(GLB_CAST(Bhi + gb), LDS_CAST(sBh + ldso), 16, 0, 0);
        }
        __syncthreads();

        bf16x8 ah[4], bh[4];
        #pragma unroll
        for (int mt = 0; mt < 4; ++mt)
            ah[mt] = *reinterpret_cast<const bf16x8*>(sAh + (wm * 64 + mt * 16 + r) * 32 + sw * 8);
        #pragma unroll
        for (int nt = 0; nt < 4; ++nt)
            bh[nt] = *reinterpret_cast<const bf16x8*>(sBh + (wn * 64 + nt * 16 + r) * 32 + sw * 8);
        #pragma unroll
        for (int mt = 0; mt < 4; ++mt)
            #pragma unroll
            for (int nt = 0; nt < 4; ++nt)
                acc[mt][nt] = __builtin_amdgcn_mfma_f32_16x16x32_bf16(ah[mt], bh[nt], acc[mt][nt], 0, 0, 0);
        __syncthreads();
    }

    #pragma unroll
    for (int nt = 0; nt < 4; ++nt) {
        const int col = wn * 64 + nt * 16 + r;
        const float bv = bias[col0 + col];
        #pragma unroll
        for (int mt = 0; mt < 4; ++mt) {
            #pragma unroll
            for (int e = 0; e < 4; ++e) {
                const int row = row0 + wm * 64 + mt * 16 + 4 * g + e;
                C[(size_t)row * ldc + col0 + col] = acc[mt][nt][e] + bv;
            }
        }
    }
}

// ---------------- split-bf16 MFMA GEMM (3-term): C = (Ahi+Alo)@(Bhi+Blo)^T + bias
template<bool RELU>
__global__ __launch_bounds__(256)
void gemm_split(const short* __restrict__ Ahi, const short* __restrict__ Alo,
                const short* __restrict__ Bhi, const short* __restrict__ Blo,
                const float* __restrict__ bias, float* __restrict__ C,
                int M, int N, int K, int ldc)
{
    __shared__ short sAh[128*32];
    __shared__ short sAl[128*32];
    __shared__ short sBh[128*32];
    __shared__ short sBl[128*32];

    const int t = threadIdx.x;
    const int lane = t & 63, wid = t >> 6;
    const int wm = wid >> 1, wn = wid & 1;
    const int row0 = blockIdx.y * 128, col0 = blockIdx.x * 128;
    const int g = lane >> 4, r = lane & 15;
    const int sw = g ^ ((lane >> 2) & 3);
    const int srow = lane >> 2;
    const int sslot = lane & 3;

    f32x4 acc[4][4];
    #pragma unroll
    for (int mt = 0; mt < 4; ++mt)
        #pragma unroll
        for (int nt = 0; nt < 4; ++nt) acc[mt][nt] = (f32x4){0.f, 0.f, 0.f, 0.f};

    for (int k0 = 0; k0 < K; k0 += 32) {
        #pragma unroll
        for (int i = 0; i < 2; ++i) {
            const int rl = wid * 32 + i * 16 + srow;
            const int scol = k0 + ((sslot ^ ((rl >> 2) & 3)) << 3);
            const size_t ga = (size_t)(row0 + rl) * K + scol;
            const size_t gb = (size_t)(col0 + rl) * K + scol;
            const int ldso = (wid * 32 + i * 16) * 32;
            __builtin_amdgcn_global_load_lds(GLB_CAST(Ahi + ga), LDS_CAST(sAh + ldso), 16, 0, 0);
            __builtin_amdgcn_global_load_lds(GLB_CAST(Alo + ga), LDS_CAST(sAl + ldso), 16, 0, 0);
            __builtin_amdgcn_global_load_lds(GLB_CAST(Bhi + gb), LDS_CAST(sBh + ldso), 16, 0, 0);
            __builtin_amdgcn_global_load_lds(GLB_CAST(Blo + gb), LDS_CAST(sBl + ldso), 16, 0, 0);
        }
        __syncthreads();

        bf16x8 ah[4], al[4], bh[4], bl[4];
        #pragma unroll
        for (int mt = 0; mt < 4; ++mt) {
            const int row = wm * 64 + mt * 16 + r;
            ah[mt] = *reinterpret_cast<const bf16x8*>(sAh + row * 32 + sw * 8);
            al[mt] = *reinterpret_cast<const bf16x8*>(sAl + row * 32 + sw * 8);
        }
        #pragma unroll
        for (int nt = 0; nt < 4; ++nt) {
            const int row = wn * 64 + nt * 16 + r;
            bh[nt] = *reinterpret_cast<const bf16x8*>(sBh + row * 32 + sw * 8);
            bl[nt] = *reinterpret_cast<const bf16x8*>(sBl + row * 32 + sw * 8);
        }
        #pragma unroll
        for (int mt = 0; mt < 4; ++mt)
            #pragma unroll
            for (int nt = 0; nt < 4; ++nt) {
                acc[mt][nt] = __builtin_amdgcn_mfma_f32_16x16x32_bf16(ah[mt], bh[nt], acc[mt][nt], 0, 0, 0);
                acc[mt][nt] = __builtin_amdgcn_mfma_f32_16x16x32_bf16(ah[mt], bl[nt], acc[mt][nt], 0, 0, 0);
                acc[mt][nt] = __builtin_amdgcn_mfma_f32_16x16x32_bf16(al[mt], bh[nt], acc[mt][nt], 0, 0, 0);
            }
        __syncthreads();
    }

    #pragma unroll
    for (int nt = 0; nt < 4; ++nt) {
        const int col = wn * 64 + nt * 16 + r;
        const float bv = bias[col0 + col];
        #pragma unroll
        for (int mt = 0; mt < 4; ++mt) {
            #pragma unroll
            for (int e = 0; e < 4; ++e) {
                const int row = row0 + wm * 64 + mt * 16 + 4 * g + e;
                float v = acc[mt][nt][e] + bv;
                if (RELU) v = fmaxf(v, 0.f);
                C[(size_t)row * ldc + col0 + col] = v;
            }
        }
    }
}

// ---------------- importance / top-k
__global__ __launch_bounds__(256)
void importance_kernel(const float* __restrict__ h, const float* __restrict__ wi2,
                       const float* __restrict__ bi2, float* __restrict__ imp)
{
    const int wid = threadIdx.x >> 6, lane = threadIdx.x & 63;
    const int row = blockIdx.x * 4 + wid;
    const float* hr = h + (size_t)row * DH;
    float s = 0.f;
    #pragma unroll
    for (int i = 0; i < DH/64; ++i)
        s = fmaf(hr[lane + i*64], wi2[lane + i*64], s);
    #pragma unroll
    for (int off = 32; off; off >>= 1) s += __shfl_down(s, off);
    if (lane == 0) imp[row] = s + bi2[0];
}

__global__ __launch_bounds__(256)
void rank_kernel(const float* __restrict__ imp, int* __restrict__ flags)
{
    const int b = blockIdx.y;
    const int i = blockIdx.x * 256 + threadIdx.x;
    const float* bimp = imp + b * SS;
    const float v = bimp[i];
    int rank = 0;
    for (int j = 0; j < SS; ++j) {
        const float u = bimp[j];
        rank += (u > v) || ((u == v) && (j < i));
    }
    flags[b * SS + i] = (rank < KSEL) ? 1 : 0;
}

__global__ __launch_bounds__(256)
void compact_kernel(const int* __restrict__ flags, int* __restrict__ idxg)
{
    __shared__ int sscan[SS];
    __shared__ int sidx[KSEL];
    const int b = blockIdx.x, t = threadIdx.x;
    for (int i = t; i < SS; i += 256) sscan[i] = flags[b * SS + i];
    __syncthreads();
    for (int off = 1; off < SS; off <<= 1) {
        int vals[SS/256];
        #pragma unroll
        for (int c = 0; c < SS/256; ++c) {
            const int i = t + c * 256;
            int v = sscan[i];
            if (i >= off) v += sscan[i - off];
            vals[c] = v;
        }
        __syncthreads();
        #pragma unroll
        for (int c = 0; c < SS/256; ++c) sscan[t + c * 256] = vals[c];
        __syncthreads();
    }
    for (int i = t; i < SS; i += 256) {
        const int f = flags[b * SS + i];
        if (f) sidx[sscan[i] - 1] = i;
    }
    __syncthreads();
    for (int p = t; p < KPAD; p += 256)
        idxg[b * KPAD + p] = sidx[min(p, KSEL - 1)];
}

// ---------------- MFMA sparse flash attention (Q plain bf16 now: 2 MFMA per kt)
__global__ __launch_bounds__(256)
void attn_mfma(const float* __restrict__ QKV, const int* __restrict__ idxg,
               short* __restrict__ AOhi, short* __restrict__ AOlo)
{
    __shared__ short Ks[64*72];
    __shared__ short Vt[64*72];
    __shared__ short Ps[4][16*72];

    const int t = threadIdx.x;
    const int lane = t & 63, w = t >> 6;
    const int g = lane >> 4, r = lane & 15;
    const int qt = blockIdx.x, h = blockIdx.y, b = blockIdx.z;
    const int q0 = qt * 64;
    const int* bidx = idxg + b * KPAD;
    short* Psw = &Ps[w][0];

    // Q fragments, pre-scaled by 1/8, plain bf16
    bf16x8 qh[2];
    {
        const float* qrow = QKV + (size_t)(b * SS + q0 + w * 16 + r) * QKVS + h * HD;
        #pragma unroll
        for (int ch = 0; ch < 2; ++ch) {
            float4 f0 = *reinterpret_cast<const float4*>(&qrow[ch*32 + 8*g]);
            float4 f1 = *reinterpret_cast<const float4*>(&qrow[ch*32 + 8*g + 4]);
            float v[8] = {f0.x, f0.y, f0.z, f0.w, f1.x, f1.y, f1.z, f1.w};
            #pragma unroll
            for (int e = 0; e < 8; ++e) qh[ch][e] = bf16rne(v[e] * 0.125f);
        }
    }

    f32x4 oacc[4];
    #pragma unroll
    for (int dt = 0; dt < 4; ++dt) oacc[dt] = (f32x4){0.f, 0.f, 0.f, 0.f};
    float mrun[4] = {-INFINITY, -INFINITY, -INFINITY, -INFINITY};
    float lrun[4] = {0.f, 0.f, 0.f, 0.f};

    const int srow = t >> 2;
    const int sq4  = t & 3;

    for (int c = 0; c < NCH; ++c) {
        __syncthreads();
        {
            const int krow = bidx[c * 64 + srow];
            const float* kb = QKV + (size_t)(b * SS + krow) * QKVS + 1024 + h * HD + sq4 * 16;
            float4 k0 = *reinterpret_cast<const float4*>(kb);
            float4 k1 = *reinterpret_cast<const float4*>(kb + 4);
            float4 k2 = *reinterpret_cast<const float4*>(kb + 8);
            float4 k3 = *reinterpret_cast<const float4*>(kb + 12);
            const float* vb = kb + 1024;
            float4 v0 = *reinterpret_cast<const float4*>(vb);
            float4 v1 = *reinterpret_cast<const float4*>(vb + 4);
            float4 v2 = *reinterpret_cast<const float4*>(vb + 8);
            float4 v3 = *reinterpret_cast<const float4*>(vb + 12);
            *reinterpret_cast<bf16x8*>(&Ks[srow*72 + sq4*16])     = pack8(k0, k1);
            *reinterpret_cast<bf16x8*>(&Ks[srow*72 + sq4*16 + 8]) = pack8(k2, k3);
            float vv[16] = {v0.x,v0.y,v0.z,v0.w, v1.x,v1.y,v1.z,v1.w,
                            v2.x,v2.y,v2.z,v2.w, v3.x,v3.y,v3.z,v3.w};
            const int vcol = srow ^ (8 * sq4);
            #pragma unroll
            for (int j = 0; j < 16; ++j)
                Vt[(sq4*16 + j)*72 + vcol] = bf16rne(vv[j]);
        }
        __syncthreads();

        f32x4 sa[4];
        #pragma unroll
        for (int kt = 0; kt < 4; ++kt) {
            bf16x8 kf0 = *reinterpret_cast<const bf16x8*>(&Ks[(kt*16 + r)*72 + 8*g]);
            bf16x8 kf1 = *reinterpret_cast<const bf16x8*>(&Ks[(kt*16 + r)*72 + 32 + 8*g]);
            f32x4 s = (f32x4){0.f, 0.f, 0.f, 0.f};
            s = __builtin_amdgcn_mfma_f32_16x16x32_bf16(qh[0], kf0, s, 0, 0, 0);
            s = __builtin_amdgcn_mfma_f32_16x16x32_bf16(qh[1], kf1, s, 0, 0, 0);
            sa[kt] = s;
        }
        if (c == NCH - 1) {
            #pragma unroll
            for (int kt = 0; kt < 4; ++kt)
                if (c*64 + kt*16 + r >= KSEL)
                    sa[kt] = (f32x4){-INFINITY, -INFINITY, -INFINITY, -INFINITY};
        }

        float p[4][4], scl[4];
        #pragma unroll
        for (int e = 0; e < 4; ++e) {
            float mx = fmaxf(fmaxf(sa[0][e], sa[1][e]), fmaxf(sa[2][e], sa[3][e]));
            #pragma unroll
            for (int off = 1; off < 16; off <<= 1) mx = fmaxf(mx, __shfl_xor(mx, off));
            const float mnew = fmaxf(mrun[e], mx);
            scl[e] = __expf(mrun[e] - mnew);
            float s0 = 0.f;
            #pragma unroll
            for (int kt = 0; kt < 4; ++kt) { p[kt][e] = __expf(sa[kt][e] - mnew); s0 += p[kt][e]; }
            #pragma unroll
            for (int off = 1; off < 16; off <<= 1) s0 += __shfl_xor(s0, off);
            lrun[e] = lrun[e] * scl[e] + s0;
            mrun[e] = mnew;
        }
        #pragma unroll
        for (int dt = 0; dt < 4; ++dt)
            #pragma unroll
            for (int e = 0; e < 4; ++e) oacc[dt][e] *= scl[e];

        #pragma unroll
        for (int kt = 0; kt < 4; ++kt)
            #pragma unroll
            for (int e = 0; e < 4; ++e)
                Psw[(4*g + e)*72 + ((kt*16 + r) ^ (8*g))] = bf16rne(p[kt][e]);

        #pragma unroll
        for (int kc = 0; kc < 2; ++kc) {
            bf16x8 pf = *reinterpret_cast<const bf16x8*>(&Psw[r*72 + kc*32 + 8*(g ^ (r >> 2))]);
            #pragma unroll
            for (int dt = 0; dt < 4; ++dt) {
                bf16x8 vf = *reinterpret_cast<const bf16x8*>(&Vt[(dt*16 + r)*72 + kc*32 + 8*(g ^ dt)]);
                oacc[dt] = __builtin_amdgcn_mfma_f32_16x16x32_bf16(pf, vf, oacc[dt], 0, 0, 0);
            }
        }
    }

    #pragma unroll
    for (int dt = 0; dt < 4; ++dt)
        #pragma unroll
        for (int e = 0; e < 4; ++e) {
            const float o = oacc[dt][e] / lrun[e];
            short hh, ll;
            split1(o, hh, ll);
            const size_t a = (size_t)(b * SS + q0 + w*16 + 4*g + e) * DD + h * HD + dt*16 + r;
            AOhi[a] = hh; AOlo[a] = ll;
        }
}

extern "C" void kernel_launch(void* const* d_in, const int* in_sizes, int n_in,
                              void* d_out, int out_size, void* d_ws, size_t ws_size,
                              hipStream_t stream)
{
    const float* x   = (const float*)d_in[0];
    const float* wq  = (const float*)d_in[1];
    const float* bq  = (const float*)d_in[2];
    const float* wk  = (const float*)d_in[3];
    const float* bk  = (const float*)d_in[4];
    const float* wv  = (const float*)d_in[5];
    const float* bv  = (const float*)d_in[6];
    const float* wo  = (const float*)d_in[7];
    const float* bo  = (const float*)d_in[8];
    const float* wi1 = (const float*)d_in[9];
    const float* bi1 = (const float*)d_in[10];
    const float* wi2 = (const float*)d_in[11];
    const float* bi2 = (const float*)d_in[12];
    float* out = (float*)d_out;

    const size_t MB = 1ull << 20;
    char* W = (char*)d_ws;
    short* x_hi  = (short*)(W + 0);          // 16 MB
    short* x_lo  = (short*)(W + 16*MB);      // 16 MB
    float* QKV   = (float*)(W + 32*MB);      // 96 MB
    short* Bqk_hi= (short*)(W + 128*MB);     // 4 MB (2048 x 1024 bf16: wq,wk)
    short* Bv_hi = (short*)(W + 132*MB);     // 2 MB
    short* Bv_lo = (short*)(W + 134*MB);     // 2 MB
    short* wo_hi = (short*)(W + 136*MB);     // 2 MB
    short* wo_lo = (short*)(W + 138*MB);     // 2 MB
    short* dead_lo = (short*)(W + 140*MB);   // 4 MB scratch for unneeded lo of wq/wk
    float* Hw    = (float*)(W + 144*MB);     // 16 MB
    float* bqk   = (float*)(W + 160*MB);
    float* imp   = (float*)(W + 160*MB + 64*1024);
    int*   flags = (int*)(W + 160*MB + 128*1024);
    int*   idxg  = (int*)(W + 160*MB + 192*1024);
    // wi1 hi/lo live inside the (not yet written) QKV region
    short* Wi_hi = (short*)(W + 32*MB);      // 1 MB
    short* Wi_lo = (short*)(W + 33*MB);      // 1 MB
    // attn output hi/lo overwrite x_hi/x_lo (dead after projections)
    short* AO_hi = x_hi;
    short* AO_lo = x_lo;

    const size_t NM = (size_t)MTOT * DD;

    // 0. splits + fused bias
    split_convert<<<(NM/4 + 255)/256, 256, 0, stream>>>(x, x_hi, x_lo, NM/4);
    split_convert<<<(DD*DD/4 + 255)/256, 256, 0, stream>>>(wq, Bqk_hi,         dead_lo,          DD*DD/4);
    split_convert<<<(DD*DD/4 + 255)/256, 256, 0, stream>>>(wk, Bqk_hi + DD*DD, dead_lo + DD*DD,  DD*DD/4);
    split_convert<<<(DD*DD/4 + 255)/256, 256, 0, stream>>>(wv, Bv_hi, Bv_lo, DD*DD/4);
    split_convert<<<(DD*DD/4 + 255)/256, 256, 0, stream>>>(wo, wo_hi, wo_lo, DD*DD/4);
    split_convert<<<(DH*DD/4 + 255)/256, 256, 0, stream>>>(wi1, Wi_hi, Wi_lo, DH*DD/4);
    concat_bias<<<2048/256, 256, 0, stream>>>(bq, bk, bqk);

    // 1. indexer h = relu(x @ wi1^T + bi1)  -- 3-term split (lo*lo ~ 1e-6, negligible)
    gemm_split<true><<<dim3(DH/128, MTOT/128), 256, 0, stream>>>(
        x_hi, x_lo, Wi_hi, Wi_lo, bi1, Hw, MTOT, DH, DD, DH);
    // 2-3. importance + top-k
    importance_kernel<<<MTOT/4, 256, 0, stream>>>(Hw, wi2, bi2, imp);
    rank_kernel<<<dim3(SS/256, BB), 256, 0, stream>>>(imp, flags);
    compact_kernel<<<BB, 256, 0, stream>>>(flags, idxg);

    // 4a. Q,K projection: pure bf16 (softmax-damped) -> QKV cols 0..2047
    gemm_bf16<<<dim3(2048/128, MTOT/128), 256, 0, stream>>>(
        x_hi, Bqk_hi, bqk, QKV, MTOT, 2048, DD, QKVS);
    // 4b. V projection: 3-term split (linear path) -> QKV cols 2048..3071
    gemm_split<false><<<dim3(DD/128, MTOT/128), 256, 0, stream>>>(
        x_hi, x_lo, Bv_hi, Bv_lo, bv, QKV + 2048, MTOT, DD, DD, QKVS);

    // 5. MFMA sparse flash attention -> bf16 hi/lo directly
    attn_mfma<<<dim3(SS/64, HHD, BB), 256, 0, stream>>>(QKV, idxg, AO_hi, AO_lo);

    // 6. output projection (3-term split: linear path)
    gemm_split<false><<<dim3(DD/128, MTOT/128), 256, 0, stream>>>(
        AO_hi, AO_lo, wo_hi, wo_lo, bo, out, MTOT, DD, DD, DD);
}